// Round 8
// baseline (2747.831 us; speedup 1.0000x reference)
//
#include <hip/hip_runtime.h>

#define BT 1024   // batch
#define TT 512    // total timesteps

__device__ __forceinline__ float sig_(float x) { return 1.f / (1.f + __expf(-x)); }
__device__ __forceinline__ float th_(float x)  { return 1.f - 2.f / (1.f + __expf(2.f * x)); }

// ---------------------------------------------------------------------------
// gemm_pre v3 (unchanged — R5 confirmed, out of top-5).
// ---------------------------------------------------------------------------
template <int KS, int KPAD, int KH, int N, bool XMODE>
__device__ __forceinline__ void gp_stage(
    const float* __restrict__ A, const float* __restrict__ W,
    float (&As)[128][KPAD], float (&Bs)[KPAD][128],
    int tid, int n0, int by, int t0, int k0)
{
    constexpr int NQH = KH / 4;
#pragma unroll
    for (int ii = tid; ii < 128 * NQH; ii += 256) {
        int r = ii / NQH, q = ii % NQH;
        const float* src;
        if (XMODE) {
            int b  = (by & 7) * 128 + r;
            int tl = by >> 3;
            src = A + ((size_t)b * TT + (t0 + tl)) * KS;
        } else {
            src = A + (size_t)(by * 128 + r) * KS;
        }
        *(float4*)&As[r][q * 4] = *(const float4*)(src + k0 + q * 4);
    }
#pragma unroll
    for (int ii = tid; ii < 128 * NQH; ii += 256) {
        int n = ii & 127, kq = ii >> 7;
        float4 v = make_float4(0.f, 0.f, 0.f, 0.f);
        if (n0 + n < N) v = *(const float4*)(W + (size_t)(n0 + n) * KS + k0 + kq * 4);
        Bs[kq * 4 + 0][n] = v.x; Bs[kq * 4 + 1][n] = v.y;
        Bs[kq * 4 + 2][n] = v.z; Bs[kq * 4 + 3][n] = v.w;
    }
}

template <int KPAD, int KH>
__device__ __forceinline__ void gp_compute(
    const float (&As)[128][KPAD], const float (&Bs)[KPAD][128],
    float (&acc)[8][8], int tx, int ty)
{
    for (int kk = 0; kk < KH; kk += 4) {
        float4 bv[4][2];
#pragma unroll
        for (int r = 0; r < 4; r++) {
            bv[r][0] = *(const float4*)&Bs[kk + r][tx * 8];
            bv[r][1] = *(const float4*)&Bs[kk + r][tx * 8 + 4];
        }
#pragma unroll
        for (int i = 0; i < 8; i++) {
            float4 av = *(const float4*)&As[ty + 16 * i][kk];
#pragma unroll
            for (int s = 0; s < 2; s++) {
                acc[i][s*4+0] = fmaf(av.x, bv[0][s].x, acc[i][s*4+0]);
                acc[i][s*4+0] = fmaf(av.y, bv[1][s].x, acc[i][s*4+0]);
                acc[i][s*4+0] = fmaf(av.z, bv[2][s].x, acc[i][s*4+0]);
                acc[i][s*4+0] = fmaf(av.w, bv[3][s].x, acc[i][s*4+0]);
                acc[i][s*4+1] = fmaf(av.x, bv[0][s].y, acc[i][s*4+1]);
                acc[i][s*4+1] = fmaf(av.y, bv[1][s].y, acc[i][s*4+1]);
                acc[i][s*4+1] = fmaf(av.z, bv[2][s].y, acc[i][s*4+1]);
                acc[i][s*4+1] = fmaf(av.w, bv[3][s].y, acc[i][s*4+1]);
                acc[i][s*4+2] = fmaf(av.x, bv[0][s].z, acc[i][s*4+2]);
                acc[i][s*4+2] = fmaf(av.y, bv[1][s].z, acc[i][s*4+2]);
                acc[i][s*4+2] = fmaf(av.z, bv[2][s].z, acc[i][s*4+2]);
                acc[i][s*4+2] = fmaf(av.w, bv[3][s].z, acc[i][s*4+2]);
                acc[i][s*4+3] = fmaf(av.x, bv[0][s].w, acc[i][s*4+3]);
                acc[i][s*4+3] = fmaf(av.y, bv[1][s].w, acc[i][s*4+3]);
                acc[i][s*4+3] = fmaf(av.z, bv[2][s].w, acc[i][s*4+3]);
                acc[i][s*4+3] = fmaf(av.w, bv[3][s].w, acc[i][s*4+3]);
            }
        }
    }
}

template <int KS, int KPAD, int KH0, int N, bool XMODE>
__global__ __launch_bounds__(256, 3) void gemm_pre(
    const float* __restrict__ A, const float* __restrict__ W,
    const float* __restrict__ bih, const float* __restrict__ bhh,
    float* __restrict__ out, int t0)
{
    constexpr int KH1 = KS - KH0;
    __shared__ __align__(16) float As[128][KPAD];
    __shared__ __align__(16) float Bs[KPAD][128];
    const int tid = threadIdx.x;
    const int n0 = blockIdx.x * 128;
    const int by = blockIdx.y;
    const int Rbase = by * 128;
    const int tx = tid & 15, ty = tid >> 4;

    float acc[8][8];
#pragma unroll
    for (int i = 0; i < 8; i++)
#pragma unroll
        for (int j = 0; j < 8; j++) acc[i][j] = 0.f;

    gp_stage<KS, KPAD, KH0, N, XMODE>(A, W, As, Bs, tid, n0, by, t0, 0);
    __syncthreads();
    gp_compute<KPAD, KH0>(As, Bs, acc, tx, ty);
    __syncthreads();
    gp_stage<KS, KPAD, KH1, N, XMODE>(A, W, As, Bs, tid, n0, by, t0, KH0);
    __syncthreads();
    gp_compute<KPAD, KH1>(As, Bs, acc, tx, ty);

#pragma unroll
    for (int s = 0; s < 2; s++) {
        int n = n0 + tx * 8 + s * 4;
        if (n < N) {
            float4 bias;
            bias.x = bih[n] + bhh[n];         bias.y = bih[n + 1] + bhh[n + 1];
            bias.z = bih[n + 2] + bhh[n + 2]; bias.w = bih[n + 3] + bhh[n + 3];
#pragma unroll
            for (int i = 0; i < 8; i++) {
                size_t R = (size_t)Rbase + ty + 16 * i;
                float4 o;
                o.x = acc[i][s*4+0] + bias.x; o.y = acc[i][s*4+1] + bias.y;
                o.z = acc[i][s*4+2] + bias.z; o.w = acc[i][s*4+3] + bias.w;
                *(float4*)(out + R * N + n) = o;
            }
        }
    }
}

// ---------------------------------------------------------------------------
// rec1 v9 = R1's v4 (118 µs, proven best) + VOLATILE weight loads.
// R7 THEORY: R3/R4/R6 proved the RA remats the guarded invariant Whh loads
// at any register budget (granted 64/72/48). volatile makes remat ILLEGAL:
// a volatile load must execute exactly once (as written), so the 80 weight
// floats must stay resident. (512,4) caps at 128 regs; worst-case live set
// ~118 fits -> no scratch. Worst realistic case: RA shunts to AGPRs ≈ R4's
// 122 µs (neutral). Everything else is byte-identical to v4.
// CONFIRMATION: VGPR_Count >= ~100, WRITE_SIZE stays 26 MB, FETCH drops.
// DO NOT use min-waves=1 (prior-session container failures).
// ---------------------------------------------------------------------------
__global__ __launch_bounds__(512, 4) void rec1(
    const float* __restrict__ pre,   // [Tc][1024][400]
    const float* __restrict__ Whh,   // [400][100]
    float* __restrict__ hseq,        // [Tc][1024][100]
    float* __restrict__ cst,         // [1024][100]
    int Tc, int first)
{
    __shared__ __align__(16) float hs[2][100];
    __shared__ __align__(16) float pres[2][800];
    __shared__ float gbuf[5 * 4 * 2 * 100];
    const int tid = threadIdx.x;
    const int b0 = blockIdx.x * 2;

    const bool comp = tid < 500;
    const int j  = tid % 100;
    const int kq = tid / 100;

    float4 w[4][5];
    if (comp) {
#pragma unroll
        for (int g = 0; g < 4; g++) {
            // volatile: loads cannot be remat'd/sunk into the t-loop
            const volatile float* Wv =
                Whh + (size_t)(g * 100 + j) * 100 + kq * 20;
#pragma unroll
            for (int q = 0; q < 5; q++) {
                w[g][q].x = Wv[q * 4 + 0];
                w[g][q].y = Wv[q * 4 + 1];
                w[g][q].z = Wv[q * 4 + 2];
                w[g][q].w = Wv[q * 4 + 3];
            }
        }
    }

    const bool upd = tid < 200;
    const int ub = tid / 100, uj = tid % 100;
    float c = 0.f;
    if (upd) {
        float h = 0.f;
        if (!first) {
            h = hseq[((size_t)(Tc - 1) * BT + b0 + ub) * 100 + uj];
            c = cst[(size_t)(b0 + ub) * 100 + uj];
        }
        hs[ub][uj] = h;
        ((float4*)pres[0])[tid] = ((const float4*)(pre + (size_t)b0 * 400))[tid];
    }
    __syncthreads();

    int cur = 0;
    for (int t = 0; t < Tc; t++) {
        int tn = (t + 1 < Tc) ? (t + 1) : t;
        float4 pf0;
        if (upd)
            pf0 = ((const float4*)(pre + (size_t)tn * BT * 400 + (size_t)b0 * 400))[tid];

        if (comp) {
            float acc[4][2];
#pragma unroll
            for (int g = 0; g < 4; g++) { acc[g][0] = 0.f; acc[g][1] = 0.f; }
            const float4* h0 = (const float4*)hs[0];
            const float4* h1 = (const float4*)hs[1];
#pragma unroll
            for (int q = 0; q < 5; q++) {
                int f = kq * 5 + q;
                float4 v0 = h0[f], v1 = h1[f];
#pragma unroll
                for (int g = 0; g < 4; g++) {
                    float4 wq = w[g][q];
                    acc[g][0] = fmaf(wq.x, v0.x, acc[g][0]);
                    acc[g][0] = fmaf(wq.y, v0.y, acc[g][0]);
                    acc[g][0] = fmaf(wq.z, v0.z, acc[g][0]);
                    acc[g][0] = fmaf(wq.w, v0.w, acc[g][0]);
                    acc[g][1] = fmaf(wq.x, v1.x, acc[g][1]);
                    acc[g][1] = fmaf(wq.y, v1.y, acc[g][1]);
                    acc[g][1] = fmaf(wq.z, v1.z, acc[g][1]);
                    acc[g][1] = fmaf(wq.w, v1.w, acc[g][1]);
                }
            }
#pragma unroll
            for (int g = 0; g < 4; g++) {
                gbuf[((kq * 4 + g) * 2 + 0) * 100 + j] = acc[g][0];
                gbuf[((kq * 4 + g) * 2 + 1) * 100 + j] = acc[g][1];
            }
        }
        __syncthreads();

        if (upd) {
            const float* pb = pres[cur];
            float s0 = 0.f, s1 = 0.f, s2 = 0.f, s3 = 0.f;
#pragma unroll
            for (int q = 0; q < 5; q++) {
                int base = q * 800;
                s0 += gbuf[base + (0 * 2 + ub) * 100 + uj];
                s1 += gbuf[base + (1 * 2 + ub) * 100 + uj];
                s2 += gbuf[base + (2 * 2 + ub) * 100 + uj];
                s3 += gbuf[base + (3 * 2 + ub) * 100 + uj];
            }
            float xi = s0 + pb[ub * 400 + uj];
            float xf = s1 + pb[ub * 400 + 100 + uj];
            float xg = s2 + pb[ub * 400 + 200 + uj];
            float xo = s3 + pb[ub * 400 + 300 + uj];
            float ii = sig_(xi), ff = sig_(xf), gg = th_(xg), oo = sig_(xo);
            c = ff * c + ii * gg;
            float h = oo * th_(c);
            hs[ub][uj] = h;
            hseq[((size_t)t * BT + b0 + ub) * 100 + uj] = h;
            ((float4*)pres[cur ^ 1])[tid] = pf0;
        }
        __syncthreads();
        cur ^= 1;
    }
    if (upd) cst[(size_t)(b0 + ub) * 100 + uj] = c;
}

// ---------------------------------------------------------------------------
// rec2 v4 (exact R1 form — proven; left untouched as control).
// ---------------------------------------------------------------------------
__global__ __launch_bounds__(256, 4) void rec2(
    const float* __restrict__ pre2,  // [Tc][1024][200]
    const float* __restrict__ Whh,   // [200][50]
    float* __restrict__ cst, float* __restrict__ hst,  // [1024][50]
    float* __restrict__ out,         // [1024][50]
    int Tc, int first)
{
    __shared__ __align__(16) float hs[2][50];
    __shared__ __align__(16) float pres[2][400];
    __shared__ float gbuf[5 * 4 * 2 * 50];
    const int tid = threadIdx.x;
    const int b0 = blockIdx.x * 2;

    const bool comp = tid < 250;
    const int j  = tid % 50;
    const int kq = tid / 50;

    float2 w[4][5];
    if (comp) {
#pragma unroll
        for (int g = 0; g < 4; g++) {
            const float2* W2 = (const float2*)(Whh + (size_t)(g * 50 + j) * 50);
#pragma unroll
            for (int q = 0; q < 5; q++) w[g][q] = W2[kq * 5 + q];
        }
    }

    const bool upd = tid < 100;
    const int ub = tid / 50, uj = tid % 50;
    float c = 0.f, hlast = 0.f;
    if (upd) {
        float h = 0.f;
        if (!first) {
            h = hst[(size_t)(b0 + ub) * 50 + uj];
            c = cst[(size_t)(b0 + ub) * 50 + uj];
        }
        hs[ub][uj] = h;
        hlast = h;
        ((float4*)pres[0])[tid] = ((const float4*)(pre2 + (size_t)b0 * 200))[tid];
    }
    __syncthreads();

    int cur = 0;
    for (int t = 0; t < Tc; t++) {
        int tn = (t + 1 < Tc) ? (t + 1) : t;
        float4 pf0;
        if (upd)
            pf0 = ((const float4*)(pre2 + (size_t)tn * BT * 200 + (size_t)b0 * 200))[tid];

        if (comp) {
            float acc[4][2];
#pragma unroll
            for (int g = 0; g < 4; g++) { acc[g][0] = 0.f; acc[g][1] = 0.f; }
            const float2* hA = (const float2*)hs[0];
            const float2* hB = (const float2*)hs[1];
#pragma unroll
            for (int q = 0; q < 5; q++) {
                int f = kq * 5 + q;
                float2 v0 = hA[f], v1 = hB[f];
#pragma unroll
                for (int g = 0; g < 4; g++) {
                    float2 wq = w[g][q];
                    acc[g][0] = fmaf(wq.x, v0.x, acc[g][0]);
                    acc[g][0] = fmaf(wq.y, v0.y, acc[g][0]);
                    acc[g][1] = fmaf(wq.x, v1.x, acc[g][1]);
                    acc[g][1] = fmaf(wq.y, v1.y, acc[g][1]);
                }
            }
#pragma unroll
            for (int g = 0; g < 4; g++) {
                gbuf[((kq * 4 + g) * 2 + 0) * 50 + j] = acc[g][0];
                gbuf[((kq * 4 + g) * 2 + 1) * 50 + j] = acc[g][1];
            }
        }
        __syncthreads();

        if (upd) {
            const float* pb = pres[cur];
            float s0 = 0.f, s1 = 0.f, s2 = 0.f, s3 = 0.f;
#pragma unroll
            for (int q = 0; q < 5; q++) {
                int base = q * 400;
                s0 += gbuf[base + (0 * 2 + ub) * 50 + uj];
                s1 += gbuf[base + (1 * 2 + ub) * 50 + uj];
                s2 += gbuf[base + (2 * 2 + ub) * 50 + uj];
                s3 += gbuf[base + (3 * 2 + ub) * 50 + uj];
            }
            float xi = s0 + pb[ub * 200 + uj];
            float xf = s1 + pb[ub * 200 + 50 + uj];
            float xg = s2 + pb[ub * 200 + 100 + uj];
            float xo = s3 + pb[ub * 200 + 150 + uj];
            float ii = sig_(xi), ff = sig_(xf), gg = th_(xg), oo = sig_(xo);
            c = ff * c + ii * gg;
            float h = oo * th_(c);
            hs[ub][uj] = h;
            hlast = h;
            ((float4*)pres[cur ^ 1])[tid] = pf0;
        }
        __syncthreads();
        cur ^= 1;
    }
    if (upd) {
        cst[(size_t)(b0 + ub) * 50 + uj] = c;
        hst[(size_t)(b0 + ub) * 50 + uj] = hlast;
        out[(size_t)(b0 + ub) * 50 + uj] = hlast;
    }
}

// ---------------------------------------------------------------------------
extern "C" void kernel_launch(void* const* d_in, const int* in_sizes, int n_in,
                              void* d_out, int out_size, void* d_ws, size_t ws_size,
                              hipStream_t stream)
{
    const float* x    = (const float*)d_in[0];
    const float* Wih1 = (const float*)d_in[1];
    const float* Whh1 = (const float*)d_in[2];
    const float* bih1 = (const float*)d_in[3];
    const float* bhh1 = (const float*)d_in[4];
    const float* Wih2 = (const float*)d_in[5];
    const float* Whh2 = (const float*)d_in[6];
    const float* bih2 = (const float*)d_in[7];
    const float* bhh2 = (const float*)d_in[8];
    float* out = (float*)d_out;
    float* ws  = (float*)d_ws;

    // Try Tc=128 (fewer launches / less serialization); need() auto-falls-back.
    int Tc = 128;
    auto need = [](int tc) -> size_t {
        return ((size_t)tc * 1024 * (400 + 100 + 200) +
                (size_t)1024 * 100 + (size_t)1024 * 50 * 2) * sizeof(float);
    };
    while (Tc > 1 && need(Tc) > ws_size) Tc >>= 1;

    float* pre1 = ws;
    float* h1s  = pre1 + (size_t)Tc * 1024 * 400;
    float* pre2 = h1s  + (size_t)Tc * 1024 * 100;
    float* c1   = pre2 + (size_t)Tc * 1024 * 200;
    float* c2   = c1 + 1024 * 100;
    float* h2st = c2 + 1024 * 50;

    const int nch = TT / Tc;
    for (int ch = 0; ch < nch; ch++) {
        int t0 = ch * Tc;
        gemm_pre<80, 40, 40, 400, true ><<<dim3(4, Tc * 8), 256, 0, stream>>>(
            x, Wih1, bih1, bhh1, pre1, t0);
        rec1<<<dim3(512), dim3(512), 0, stream>>>(pre1, Whh1, h1s, c1, Tc, ch == 0 ? 1 : 0);
        gemm_pre<100, 52, 52, 200, false><<<dim3(2, Tc * 8), 256, 0, stream>>>(
            h1s, Wih2, bih2, bhh2, pre2, 0);
        rec2<<<dim3(512), dim3(256), 0, stream>>>(pre2, Whh2, c2, h2st, out, Tc, ch == 0 ? 1 : 0);
    }
}

// Round 9
// 2528.690 us; speedup vs baseline: 1.0867x; 1.0867x over previous
//
#include <hip/hip_runtime.h>

#define BT 1024   // batch
#define TT 512    // total timesteps

__device__ __forceinline__ float sig_(float x) { return 1.f / (1.f + __expf(-x)); }
__device__ __forceinline__ float th_(float x)  { return 1.f - 2.f / (1.f + __expf(2.f * x)); }

// ---------------------------------------------------------------------------
// gemm_pre v3 (R5, verified: saved ~115 µs vs v2, out of top-5 since).
// 8x8 micro-tile, 128-col blocks, two staged K-halves, strided rows.
// ---------------------------------------------------------------------------
template <int KS, int KPAD, int KH, int N, bool XMODE>
__device__ __forceinline__ void gp_stage(
    const float* __restrict__ A, const float* __restrict__ W,
    float (&As)[128][KPAD], float (&Bs)[KPAD][128],
    int tid, int n0, int by, int t0, int k0)
{
    constexpr int NQH = KH / 4;
#pragma unroll
    for (int ii = tid; ii < 128 * NQH; ii += 256) {
        int r = ii / NQH, q = ii % NQH;
        const float* src;
        if (XMODE) {
            int b  = (by & 7) * 128 + r;
            int tl = by >> 3;
            src = A + ((size_t)b * TT + (t0 + tl)) * KS;
        } else {
            src = A + (size_t)(by * 128 + r) * KS;
        }
        *(float4*)&As[r][q * 4] = *(const float4*)(src + k0 + q * 4);
    }
#pragma unroll
    for (int ii = tid; ii < 128 * NQH; ii += 256) {
        int n = ii & 127, kq = ii >> 7;
        float4 v = make_float4(0.f, 0.f, 0.f, 0.f);
        if (n0 + n < N) v = *(const float4*)(W + (size_t)(n0 + n) * KS + k0 + kq * 4);
        Bs[kq * 4 + 0][n] = v.x; Bs[kq * 4 + 1][n] = v.y;
        Bs[kq * 4 + 2][n] = v.z; Bs[kq * 4 + 3][n] = v.w;
    }
}

template <int KPAD, int KH>
__device__ __forceinline__ void gp_compute(
    const float (&As)[128][KPAD], const float (&Bs)[KPAD][128],
    float (&acc)[8][8], int tx, int ty)
{
    for (int kk = 0; kk < KH; kk += 4) {
        float4 bv[4][2];
#pragma unroll
        for (int r = 0; r < 4; r++) {
            bv[r][0] = *(const float4*)&Bs[kk + r][tx * 8];
            bv[r][1] = *(const float4*)&Bs[kk + r][tx * 8 + 4];
        }
#pragma unroll
        for (int i = 0; i < 8; i++) {
            float4 av = *(const float4*)&As[ty + 16 * i][kk];
#pragma unroll
            for (int s = 0; s < 2; s++) {
                acc[i][s*4+0] = fmaf(av.x, bv[0][s].x, acc[i][s*4+0]);
                acc[i][s*4+0] = fmaf(av.y, bv[1][s].x, acc[i][s*4+0]);
                acc[i][s*4+0] = fmaf(av.z, bv[2][s].x, acc[i][s*4+0]);
                acc[i][s*4+0] = fmaf(av.w, bv[3][s].x, acc[i][s*4+0]);
                acc[i][s*4+1] = fmaf(av.x, bv[0][s].y, acc[i][s*4+1]);
                acc[i][s*4+1] = fmaf(av.y, bv[1][s].y, acc[i][s*4+1]);
                acc[i][s*4+1] = fmaf(av.z, bv[2][s].y, acc[i][s*4+1]);
                acc[i][s*4+1] = fmaf(av.w, bv[3][s].y, acc[i][s*4+1]);
                acc[i][s*4+2] = fmaf(av.x, bv[0][s].z, acc[i][s*4+2]);
                acc[i][s*4+2] = fmaf(av.y, bv[1][s].z, acc[i][s*4+2]);
                acc[i][s*4+2] = fmaf(av.z, bv[2][s].z, acc[i][s*4+2]);
                acc[i][s*4+2] = fmaf(av.w, bv[3][s].z, acc[i][s*4+2]);
                acc[i][s*4+3] = fmaf(av.x, bv[0][s].w, acc[i][s*4+3]);
                acc[i][s*4+3] = fmaf(av.y, bv[1][s].w, acc[i][s*4+3]);
                acc[i][s*4+3] = fmaf(av.z, bv[2][s].w, acc[i][s*4+3]);
                acc[i][s*4+3] = fmaf(av.w, bv[3][s].w, acc[i][s*4+3]);
            }
        }
    }
}

template <int KS, int KPAD, int KH0, int N, bool XMODE>
__global__ __launch_bounds__(256, 3) void gemm_pre(
    const float* __restrict__ A, const float* __restrict__ W,
    const float* __restrict__ bih, const float* __restrict__ bhh,
    float* __restrict__ out, int t0)
{
    constexpr int KH1 = KS - KH0;
    __shared__ __align__(16) float As[128][KPAD];
    __shared__ __align__(16) float Bs[KPAD][128];
    const int tid = threadIdx.x;
    const int n0 = blockIdx.x * 128;
    const int by = blockIdx.y;
    const int Rbase = by * 128;
    const int tx = tid & 15, ty = tid >> 4;

    float acc[8][8];
#pragma unroll
    for (int i = 0; i < 8; i++)
#pragma unroll
        for (int j = 0; j < 8; j++) acc[i][j] = 0.f;

    gp_stage<KS, KPAD, KH0, N, XMODE>(A, W, As, Bs, tid, n0, by, t0, 0);
    __syncthreads();
    gp_compute<KPAD, KH0>(As, Bs, acc, tx, ty);
    __syncthreads();
    gp_stage<KS, KPAD, KH1, N, XMODE>(A, W, As, Bs, tid, n0, by, t0, KH0);
    __syncthreads();
    gp_compute<KPAD, KH1>(As, Bs, acc, tx, ty);

#pragma unroll
    for (int s = 0; s < 2; s++) {
        int n = n0 + tx * 8 + s * 4;
        if (n < N) {
            float4 bias;
            bias.x = bih[n] + bhh[n];         bias.y = bih[n + 1] + bhh[n + 1];
            bias.z = bih[n + 2] + bhh[n + 2]; bias.w = bih[n + 3] + bhh[n + 3];
#pragma unroll
            for (int i = 0; i < 8; i++) {
                size_t R = (size_t)Rbase + ty + 16 * i;
                float4 o;
                o.x = acc[i][s*4+0] + bias.x; o.y = acc[i][s*4+1] + bias.y;
                o.z = acc[i][s*4+2] + bias.z; o.w = acc[i][s*4+3] + bias.w;
                *(float4*)(out + R * N + n) = o;
            }
        }
    }
}

// ---------------------------------------------------------------------------
// rec1 v4 EXACT (R1's 118 µs form — best of 7 variants).
// LEDGER (do not retry): (512,2) → RA still remats + occupancy loss (R3);
// PIN to regs → AGPR shuffle, neutral (R4); t-unroll x2 → scratch spill
// (R5); 1024-thr/4-batch/1-WG → lost WG interleave + conflicts (R6);
// volatile → no VGPR change, no gain (R7/R8). The RA remats the guarded
// invariant weight loads at ANY budget, AND removing the traffic (R4) is
// neutral — 118 µs is this structure's plateau (mix of VALU ~1280 cyc/t,
// DS, barriers, serial update). DO NOT use min-waves=1.
// ---------------------------------------------------------------------------
__global__ __launch_bounds__(512, 4) void rec1(
    const float* __restrict__ pre,   // [Tc][1024][400]
    const float* __restrict__ Whh,   // [400][100]
    float* __restrict__ hseq,        // [Tc][1024][100]
    float* __restrict__ cst,         // [1024][100]
    int Tc, int first)
{
    __shared__ __align__(16) float hs[2][100];
    __shared__ __align__(16) float pres[2][800];
    __shared__ float gbuf[5 * 4 * 2 * 100];
    const int tid = threadIdx.x;
    const int b0 = blockIdx.x * 2;

    const bool comp = tid < 500;
    const int j  = tid % 100;
    const int kq = tid / 100;

    float4 w[4][5];
    if (comp) {
#pragma unroll
        for (int g = 0; g < 4; g++) {
            const float4* W4 = (const float4*)(Whh + (size_t)(g * 100 + j) * 100);
#pragma unroll
            for (int q = 0; q < 5; q++) w[g][q] = W4[kq * 5 + q];
        }
    }

    const bool upd = tid < 200;
    const int ub = tid / 100, uj = tid % 100;
    float c = 0.f;
    if (upd) {
        float h = 0.f;
        if (!first) {
            h = hseq[((size_t)(Tc - 1) * BT + b0 + ub) * 100 + uj];
            c = cst[(size_t)(b0 + ub) * 100 + uj];
        }
        hs[ub][uj] = h;
        ((float4*)pres[0])[tid] = ((const float4*)(pre + (size_t)b0 * 400))[tid];
    }
    __syncthreads();

    int cur = 0;
    for (int t = 0; t < Tc; t++) {
        int tn = (t + 1 < Tc) ? (t + 1) : t;
        float4 pf0;
        if (upd)
            pf0 = ((const float4*)(pre + (size_t)tn * BT * 400 + (size_t)b0 * 400))[tid];

        if (comp) {
            float acc[4][2];
#pragma unroll
            for (int g = 0; g < 4; g++) { acc[g][0] = 0.f; acc[g][1] = 0.f; }
            const float4* h0 = (const float4*)hs[0];
            const float4* h1 = (const float4*)hs[1];
#pragma unroll
            for (int q = 0; q < 5; q++) {
                int f = kq * 5 + q;
                float4 v0 = h0[f], v1 = h1[f];
#pragma unroll
                for (int g = 0; g < 4; g++) {
                    float4 wq = w[g][q];
                    acc[g][0] = fmaf(wq.x, v0.x, acc[g][0]);
                    acc[g][0] = fmaf(wq.y, v0.y, acc[g][0]);
                    acc[g][0] = fmaf(wq.z, v0.z, acc[g][0]);
                    acc[g][0] = fmaf(wq.w, v0.w, acc[g][0]);
                    acc[g][1] = fmaf(wq.x, v1.x, acc[g][1]);
                    acc[g][1] = fmaf(wq.y, v1.y, acc[g][1]);
                    acc[g][1] = fmaf(wq.z, v1.z, acc[g][1]);
                    acc[g][1] = fmaf(wq.w, v1.w, acc[g][1]);
                }
            }
#pragma unroll
            for (int g = 0; g < 4; g++) {
                gbuf[((kq * 4 + g) * 2 + 0) * 100 + j] = acc[g][0];
                gbuf[((kq * 4 + g) * 2 + 1) * 100 + j] = acc[g][1];
            }
        }
        __syncthreads();

        if (upd) {
            const float* pb = pres[cur];
            float s0 = 0.f, s1 = 0.f, s2 = 0.f, s3 = 0.f;
#pragma unroll
            for (int q = 0; q < 5; q++) {
                int base = q * 800;
                s0 += gbuf[base + (0 * 2 + ub) * 100 + uj];
                s1 += gbuf[base + (1 * 2 + ub) * 100 + uj];
                s2 += gbuf[base + (2 * 2 + ub) * 100 + uj];
                s3 += gbuf[base + (3 * 2 + ub) * 100 + uj];
            }
            float xi = s0 + pb[ub * 400 + uj];
            float xf = s1 + pb[ub * 400 + 100 + uj];
            float xg = s2 + pb[ub * 400 + 200 + uj];
            float xo = s3 + pb[ub * 400 + 300 + uj];
            float ii = sig_(xi), ff = sig_(xf), gg = th_(xg), oo = sig_(xo);
            c = ff * c + ii * gg;
            float h = oo * th_(c);
            hs[ub][uj] = h;
            hseq[((size_t)t * BT + b0 + ub) * 100 + uj] = h;
            ((float4*)pres[cur ^ 1])[tid] = pf0;
        }
        __syncthreads();
        cur ^= 1;
    }
    if (upd) cst[(size_t)(b0 + ub) * 100 + uj] = c;
}

// ---------------------------------------------------------------------------
// rec2 v4 EXACT (R1 form — proven).
// ---------------------------------------------------------------------------
__global__ __launch_bounds__(256, 4) void rec2(
    const float* __restrict__ pre2,  // [Tc][1024][200]
    const float* __restrict__ Whh,   // [200][50]
    float* __restrict__ cst, float* __restrict__ hst,  // [1024][50]
    float* __restrict__ out,         // [1024][50]
    int Tc, int first)
{
    __shared__ __align__(16) float hs[2][50];
    __shared__ __align__(16) float pres[2][400];
    __shared__ float gbuf[5 * 4 * 2 * 50];
    const int tid = threadIdx.x;
    const int b0 = blockIdx.x * 2;

    const bool comp = tid < 250;
    const int j  = tid % 50;
    const int kq = tid / 50;

    float2 w[4][5];
    if (comp) {
#pragma unroll
        for (int g = 0; g < 4; g++) {
            const float2* W2 = (const float2*)(Whh + (size_t)(g * 50 + j) * 50);
#pragma unroll
            for (int q = 0; q < 5; q++) w[g][q] = W2[kq * 5 + q];
        }
    }

    const bool upd = tid < 100;
    const int ub = tid / 50, uj = tid % 50;
    float c = 0.f, hlast = 0.f;
    if (upd) {
        float h = 0.f;
        if (!first) {
            h = hst[(size_t)(b0 + ub) * 50 + uj];
            c = cst[(size_t)(b0 + ub) * 50 + uj];
        }
        hs[ub][uj] = h;
        hlast = h;
        ((float4*)pres[0])[tid] = ((const float4*)(pre2 + (size_t)b0 * 200))[tid];
    }
    __syncthreads();

    int cur = 0;
    for (int t = 0; t < Tc; t++) {
        int tn = (t + 1 < Tc) ? (t + 1) : t;
        float4 pf0;
        if (upd)
            pf0 = ((const float4*)(pre2 + (size_t)tn * BT * 200 + (size_t)b0 * 200))[tid];

        if (comp) {
            float acc[4][2];
#pragma unroll
            for (int g = 0; g < 4; g++) { acc[g][0] = 0.f; acc[g][1] = 0.f; }
            const float2* hA = (const float2*)hs[0];
            const float2* hB = (const float2*)hs[1];
#pragma unroll
            for (int q = 0; q < 5; q++) {
                int f = kq * 5 + q;
                float2 v0 = hA[f], v1 = hB[f];
#pragma unroll
                for (int g = 0; g < 4; g++) {
                    float2 wq = w[g][q];
                    acc[g][0] = fmaf(wq.x, v0.x, acc[g][0]);
                    acc[g][0] = fmaf(wq.y, v0.y, acc[g][0]);
                    acc[g][1] = fmaf(wq.x, v1.x, acc[g][1]);
                    acc[g][1] = fmaf(wq.y, v1.y, acc[g][1]);
                }
            }
#pragma unroll
            for (int g = 0; g < 4; g++) {
                gbuf[((kq * 4 + g) * 2 + 0) * 50 + j] = acc[g][0];
                gbuf[((kq * 4 + g) * 2 + 1) * 50 + j] = acc[g][1];
            }
        }
        __syncthreads();

        if (upd) {
            const float* pb = pres[cur];
            float s0 = 0.f, s1 = 0.f, s2 = 0.f, s3 = 0.f;
#pragma unroll
            for (int q = 0; q < 5; q++) {
                int base = q * 400;
                s0 += gbuf[base + (0 * 2 + ub) * 50 + uj];
                s1 += gbuf[base + (1 * 2 + ub) * 50 + uj];
                s2 += gbuf[base + (2 * 2 + ub) * 50 + uj];
                s3 += gbuf[base + (3 * 2 + ub) * 50 + uj];
            }
            float xi = s0 + pb[ub * 200 + uj];
            float xf = s1 + pb[ub * 200 + 50 + uj];
            float xg = s2 + pb[ub * 200 + 100 + uj];
            float xo = s3 + pb[ub * 200 + 150 + uj];
            float ii = sig_(xi), ff = sig_(xf), gg = th_(xg), oo = sig_(xo);
            c = ff * c + ii * gg;
            float h = oo * th_(c);
            hs[ub][uj] = h;
            hlast = h;
            ((float4*)pres[cur ^ 1])[tid] = pf0;
        }
        __syncthreads();
        cur ^= 1;
    }
    if (upd) {
        cst[(size_t)(b0 + ub) * 50 + uj] = c;
        hst[(size_t)(b0 + ub) * 50 + uj] = hlast;
        out[(size_t)(b0 + ub) * 50 + uj] = hlast;
    }
}

// ---------------------------------------------------------------------------
extern "C" void kernel_launch(void* const* d_in, const int* in_sizes, int n_in,
                              void* d_out, int out_size, void* d_ws, size_t ws_size,
                              hipStream_t stream)
{
    const float* x    = (const float*)d_in[0];
    const float* Wih1 = (const float*)d_in[1];
    const float* Whh1 = (const float*)d_in[2];
    const float* bih1 = (const float*)d_in[3];
    const float* bhh1 = (const float*)d_in[4];
    const float* Wih2 = (const float*)d_in[5];
    const float* Whh2 = (const float*)d_in[6];
    const float* bih2 = (const float*)d_in[7];
    const float* bhh2 = (const float*)d_in[8];
    float* out = (float*)d_out;
    float* ws  = (float*)d_ws;

    // Tc=64 (R8 proved Tc=128 regresses rec1 ~30% via L3 pressure on pre1).
    int Tc = 64;
    auto need = [](int tc) -> size_t {
        return ((size_t)tc * 1024 * (400 + 100 + 200) +
                (size_t)1024 * 100 + (size_t)1024 * 50 * 2) * sizeof(float);
    };
    while (Tc > 1 && need(Tc) > ws_size) Tc >>= 1;

    float* pre1 = ws;
    float* h1s  = pre1 + (size_t)Tc * 1024 * 400;
    float* pre2 = h1s  + (size_t)Tc * 1024 * 100;
    float* c1   = pre2 + (size_t)Tc * 1024 * 200;
    float* c2   = c1 + 1024 * 100;
    float* h2st = c2 + 1024 * 50;

    const int nch = TT / Tc;
    for (int ch = 0; ch < nch; ch++) {
        int t0 = ch * Tc;
        gemm_pre<80, 40, 40, 400, true ><<<dim3(4, Tc * 8), 256, 0, stream>>>(
            x, Wih1, bih1, bhh1, pre1, t0);
        rec1<<<dim3(512), dim3(512), 0, stream>>>(pre1, Whh1, h1s, c1, Tc, ch == 0 ? 1 : 0);
        gemm_pre<100, 52, 52, 200, false><<<dim3(2, Tc * 8), 256, 0, stream>>>(
            h1s, Wih2, bih2, bhh2, pre2, 0);
        rec2<<<dim3(512), dim3(256), 0, stream>>>(pre2, Whh2, c2, h2st, out, Tc, ch == 0 ? 1 : 0);
    }
}

// Round 10
// 2458.194 us; speedup vs baseline: 1.1178x; 1.0287x over previous
//
#include <hip/hip_runtime.h>

#define BT 1024   // batch
#define TT 512    // total timesteps

__device__ __forceinline__ float sig_(float x) { return 1.f / (1.f + __expf(-x)); }
__device__ __forceinline__ float th_(float x)  { return 1.f - 2.f / (1.f + __expf(2.f * x)); }

// ---------------------------------------------------------------------------
// gemm_pre v3 (R5, verified — unchanged).
// ---------------------------------------------------------------------------
template <int KS, int KPAD, int KH, int N, bool XMODE>
__device__ __forceinline__ void gp_stage(
    const float* __restrict__ A, const float* __restrict__ W,
    float (&As)[128][KPAD], float (&Bs)[KPAD][128],
    int tid, int n0, int by, int t0, int k0)
{
    constexpr int NQH = KH / 4;
#pragma unroll
    for (int ii = tid; ii < 128 * NQH; ii += 256) {
        int r = ii / NQH, q = ii % NQH;
        const float* src;
        if (XMODE) {
            int b  = (by & 7) * 128 + r;
            int tl = by >> 3;
            src = A + ((size_t)b * TT + (t0 + tl)) * KS;
        } else {
            src = A + (size_t)(by * 128 + r) * KS;
        }
        *(float4*)&As[r][q * 4] = *(const float4*)(src + k0 + q * 4);
    }
#pragma unroll
    for (int ii = tid; ii < 128 * NQH; ii += 256) {
        int n = ii & 127, kq = ii >> 7;
        float4 v = make_float4(0.f, 0.f, 0.f, 0.f);
        if (n0 + n < N) v = *(const float4*)(W + (size_t)(n0 + n) * KS + k0 + kq * 4);
        Bs[kq * 4 + 0][n] = v.x; Bs[kq * 4 + 1][n] = v.y;
        Bs[kq * 4 + 2][n] = v.z; Bs[kq * 4 + 3][n] = v.w;
    }
}

template <int KPAD, int KH>
__device__ __forceinline__ void gp_compute(
    const float (&As)[128][KPAD], const float (&Bs)[KPAD][128],
    float (&acc)[8][8], int tx, int ty)
{
    for (int kk = 0; kk < KH; kk += 4) {
        float4 bv[4][2];
#pragma unroll
        for (int r = 0; r < 4; r++) {
            bv[r][0] = *(const float4*)&Bs[kk + r][tx * 8];
            bv[r][1] = *(const float4*)&Bs[kk + r][tx * 8 + 4];
        }
#pragma unroll
        for (int i = 0; i < 8; i++) {
            float4 av = *(const float4*)&As[ty + 16 * i][kk];
#pragma unroll
            for (int s = 0; s < 2; s++) {
                acc[i][s*4+0] = fmaf(av.x, bv[0][s].x, acc[i][s*4+0]);
                acc[i][s*4+0] = fmaf(av.y, bv[1][s].x, acc[i][s*4+0]);
                acc[i][s*4+0] = fmaf(av.z, bv[2][s].x, acc[i][s*4+0]);
                acc[i][s*4+0] = fmaf(av.w, bv[3][s].x, acc[i][s*4+0]);
                acc[i][s*4+1] = fmaf(av.x, bv[0][s].y, acc[i][s*4+1]);
                acc[i][s*4+1] = fmaf(av.y, bv[1][s].y, acc[i][s*4+1]);
                acc[i][s*4+1] = fmaf(av.z, bv[2][s].y, acc[i][s*4+1]);
                acc[i][s*4+1] = fmaf(av.w, bv[3][s].y, acc[i][s*4+1]);
                acc[i][s*4+2] = fmaf(av.x, bv[0][s].z, acc[i][s*4+2]);
                acc[i][s*4+2] = fmaf(av.y, bv[1][s].z, acc[i][s*4+2]);
                acc[i][s*4+2] = fmaf(av.z, bv[2][s].z, acc[i][s*4+2]);
                acc[i][s*4+2] = fmaf(av.w, bv[3][s].z, acc[i][s*4+2]);
                acc[i][s*4+3] = fmaf(av.x, bv[0][s].w, acc[i][s*4+3]);
                acc[i][s*4+3] = fmaf(av.y, bv[1][s].w, acc[i][s*4+3]);
                acc[i][s*4+3] = fmaf(av.z, bv[2][s].w, acc[i][s*4+3]);
                acc[i][s*4+3] = fmaf(av.w, bv[3][s].w, acc[i][s*4+3]);
            }
        }
    }
}

template <int KS, int KPAD, int KH0, int N, bool XMODE>
__global__ __launch_bounds__(256, 3) void gemm_pre(
    const float* __restrict__ A, const float* __restrict__ W,
    const float* __restrict__ bih, const float* __restrict__ bhh,
    float* __restrict__ out, int t0)
{
    constexpr int KH1 = KS - KH0;
    __shared__ __align__(16) float As[128][KPAD];
    __shared__ __align__(16) float Bs[KPAD][128];
    const int tid = threadIdx.x;
    const int n0 = blockIdx.x * 128;
    const int by = blockIdx.y;
    const int Rbase = by * 128;
    const int tx = tid & 15, ty = tid >> 4;

    float acc[8][8];
#pragma unroll
    for (int i = 0; i < 8; i++)
#pragma unroll
        for (int j = 0; j < 8; j++) acc[i][j] = 0.f;

    gp_stage<KS, KPAD, KH0, N, XMODE>(A, W, As, Bs, tid, n0, by, t0, 0);
    __syncthreads();
    gp_compute<KPAD, KH0>(As, Bs, acc, tx, ty);
    __syncthreads();
    gp_stage<KS, KPAD, KH1, N, XMODE>(A, W, As, Bs, tid, n0, by, t0, KH0);
    __syncthreads();
    gp_compute<KPAD, KH1>(As, Bs, acc, tx, ty);

#pragma unroll
    for (int s = 0; s < 2; s++) {
        int n = n0 + tx * 8 + s * 4;
        if (n < N) {
            float4 bias;
            bias.x = bih[n] + bhh[n];         bias.y = bih[n + 1] + bhh[n + 1];
            bias.z = bih[n + 2] + bhh[n + 2]; bias.w = bih[n + 3] + bhh[n + 3];
#pragma unroll
            for (int i = 0; i < 8; i++) {
                size_t R = (size_t)Rbase + ty + 16 * i;
                float4 o;
                o.x = acc[i][s*4+0] + bias.x; o.y = acc[i][s*4+1] + bias.y;
                o.z = acc[i][s*4+2] + bias.z; o.w = acc[i][s*4+3] + bias.w;
                *(float4*)(out + R * N + n) = o;
            }
        }
    }
}

// ---------------------------------------------------------------------------
// rec bodies — byte-identical math to the R1 v4 kernels (proven best).
// LEDGER (do not retry on rec1): (512,2) remat+occupancy loss (R3); PIN ->
// AGPR shuffle neutral (R4); t-unroll x2 -> spill (R5); 1024-thr/1-WG (R6);
// volatile (R7). 118 µs is the structure's plateau. R9: the remaining lever
// is SCHEDULING — rec1(ch) and rec2(ch-1) are independent & both
// latency-bound (37% occ) -> co-residency hides rec2 under rec1.
// ---------------------------------------------------------------------------
struct __align__(16) R1S {
    float hs[2][100];
    float pres[2][800];
    float gbuf[5 * 4 * 2 * 100];
};
struct __align__(16) R2S {
    float hs[2][50];
    float pres[2][400];
    float gbuf[5 * 4 * 2 * 50];
};
union __align__(16) FS { R1S r1; R2S r2[2]; };

__device__ __forceinline__ void rec1_body(
    R1S& s, int tid, int b0,
    const float* __restrict__ pre, const float* __restrict__ Whh,
    float* __restrict__ hseq, float* __restrict__ cst, int Tc, int first)
{
    const bool comp = tid < 500;
    const int j  = tid % 100;
    const int kq = tid / 100;

    float4 w[4][5];
    if (comp) {
#pragma unroll
        for (int g = 0; g < 4; g++) {
            const float4* W4 = (const float4*)(Whh + (size_t)(g * 100 + j) * 100);
#pragma unroll
            for (int q = 0; q < 5; q++) w[g][q] = W4[kq * 5 + q];
        }
    }

    const bool upd = tid < 200;
    const int ub = tid / 100, uj = tid % 100;
    float c = 0.f;
    if (upd) {
        float h = 0.f;
        if (!first) {
            h = hseq[((size_t)(Tc - 1) * BT + b0 + ub) * 100 + uj];
            c = cst[(size_t)(b0 + ub) * 100 + uj];
        }
        s.hs[ub][uj] = h;
        ((float4*)s.pres[0])[tid] = ((const float4*)(pre + (size_t)b0 * 400))[tid];
    }
    __syncthreads();

    int cur = 0;
    for (int t = 0; t < Tc; t++) {
        int tn = (t + 1 < Tc) ? (t + 1) : t;
        float4 pf0;
        if (upd)
            pf0 = ((const float4*)(pre + (size_t)tn * BT * 400 + (size_t)b0 * 400))[tid];

        if (comp) {
            float acc[4][2];
#pragma unroll
            for (int g = 0; g < 4; g++) { acc[g][0] = 0.f; acc[g][1] = 0.f; }
            const float4* h0 = (const float4*)s.hs[0];
            const float4* h1 = (const float4*)s.hs[1];
#pragma unroll
            for (int q = 0; q < 5; q++) {
                int f = kq * 5 + q;
                float4 v0 = h0[f], v1 = h1[f];
#pragma unroll
                for (int g = 0; g < 4; g++) {
                    float4 wq = w[g][q];
                    acc[g][0] = fmaf(wq.x, v0.x, acc[g][0]);
                    acc[g][0] = fmaf(wq.y, v0.y, acc[g][0]);
                    acc[g][0] = fmaf(wq.z, v0.z, acc[g][0]);
                    acc[g][0] = fmaf(wq.w, v0.w, acc[g][0]);
                    acc[g][1] = fmaf(wq.x, v1.x, acc[g][1]);
                    acc[g][1] = fmaf(wq.y, v1.y, acc[g][1]);
                    acc[g][1] = fmaf(wq.z, v1.z, acc[g][1]);
                    acc[g][1] = fmaf(wq.w, v1.w, acc[g][1]);
                }
            }
#pragma unroll
            for (int g = 0; g < 4; g++) {
                s.gbuf[((kq * 4 + g) * 2 + 0) * 100 + j] = acc[g][0];
                s.gbuf[((kq * 4 + g) * 2 + 1) * 100 + j] = acc[g][1];
            }
        }
        __syncthreads();

        if (upd) {
            const float* pb = s.pres[cur];
            float s0 = 0.f, s1 = 0.f, s2 = 0.f, s3 = 0.f;
#pragma unroll
            for (int q = 0; q < 5; q++) {
                int base = q * 800;
                s0 += s.gbuf[base + (0 * 2 + ub) * 100 + uj];
                s1 += s.gbuf[base + (1 * 2 + ub) * 100 + uj];
                s2 += s.gbuf[base + (2 * 2 + ub) * 100 + uj];
                s3 += s.gbuf[base + (3 * 2 + ub) * 100 + uj];
            }
            float xi = s0 + pb[ub * 400 + uj];
            float xf = s1 + pb[ub * 400 + 100 + uj];
            float xg = s2 + pb[ub * 400 + 200 + uj];
            float xo = s3 + pb[ub * 400 + 300 + uj];
            float ii = sig_(xi), ff = sig_(xf), gg = th_(xg), oo = sig_(xo);
            c = ff * c + ii * gg;
            float h = oo * th_(c);
            s.hs[ub][uj] = h;
            hseq[((size_t)t * BT + b0 + ub) * 100 + uj] = h;
            ((float4*)s.pres[cur ^ 1])[tid] = pf0;
        }
        __syncthreads();
        cur ^= 1;
    }
    if (upd) cst[(size_t)(b0 + ub) * 100 + uj] = c;
}

__device__ __forceinline__ void rec2_body(
    R2S& s, int tid, int b0,
    const float* __restrict__ pre2, const float* __restrict__ Whh,
    float* __restrict__ cst, float* __restrict__ hst, float* __restrict__ out,
    int Tc, int first)
{
    const bool comp = tid < 250;
    const int j  = tid % 50;
    const int kq = tid / 50;

    float2 w[4][5];
    if (comp) {
#pragma unroll
        for (int g = 0; g < 4; g++) {
            const float2* W2 = (const float2*)(Whh + (size_t)(g * 50 + j) * 50);
#pragma unroll
            for (int q = 0; q < 5; q++) w[g][q] = W2[kq * 5 + q];
        }
    }

    const bool upd = tid < 100;
    const int ub = tid / 50, uj = tid % 50;
    float c = 0.f, hlast = 0.f;
    if (upd) {
        float h = 0.f;
        if (!first) {
            h = hst[(size_t)(b0 + ub) * 50 + uj];
            c = cst[(size_t)(b0 + ub) * 50 + uj];
        }
        s.hs[ub][uj] = h;
        hlast = h;
        ((float4*)s.pres[0])[tid] = ((const float4*)(pre2 + (size_t)b0 * 200))[tid];
    }
    __syncthreads();

    int cur = 0;
    for (int t = 0; t < Tc; t++) {
        int tn = (t + 1 < Tc) ? (t + 1) : t;
        float4 pf0;
        if (upd)
            pf0 = ((const float4*)(pre2 + (size_t)tn * BT * 200 + (size_t)b0 * 200))[tid];

        if (comp) {
            float acc[4][2];
#pragma unroll
            for (int g = 0; g < 4; g++) { acc[g][0] = 0.f; acc[g][1] = 0.f; }
            const float2* hA = (const float2*)s.hs[0];
            const float2* hB = (const float2*)s.hs[1];
#pragma unroll
            for (int q = 0; q < 5; q++) {
                int f = kq * 5 + q;
                float2 v0 = hA[f], v1 = hB[f];
#pragma unroll
                for (int g = 0; g < 4; g++) {
                    float2 wq = w[g][q];
                    acc[g][0] = fmaf(wq.x, v0.x, acc[g][0]);
                    acc[g][0] = fmaf(wq.y, v0.y, acc[g][0]);
                    acc[g][1] = fmaf(wq.x, v1.x, acc[g][1]);
                    acc[g][1] = fmaf(wq.y, v1.y, acc[g][1]);
                }
            }
#pragma unroll
            for (int g = 0; g < 4; g++) {
                s.gbuf[((kq * 4 + g) * 2 + 0) * 50 + j] = acc[g][0];
                s.gbuf[((kq * 4 + g) * 2 + 1) * 50 + j] = acc[g][1];
            }
        }
        __syncthreads();

        if (upd) {
            const float* pb = s.pres[cur];
            float s0 = 0.f, s1 = 0.f, s2 = 0.f, s3 = 0.f;
#pragma unroll
            for (int q = 0; q < 5; q++) {
                int base = q * 400;
                s0 += s.gbuf[base + (0 * 2 + ub) * 50 + uj];
                s1 += s.gbuf[base + (1 * 2 + ub) * 50 + uj];
                s2 += s.gbuf[base + (2 * 2 + ub) * 50 + uj];
                s3 += s.gbuf[base + (3 * 2 + ub) * 50 + uj];
            }
            float xi = s0 + pb[ub * 200 + uj];
            float xf = s1 + pb[ub * 200 + 50 + uj];
            float xg = s2 + pb[ub * 200 + 100 + uj];
            float xo = s3 + pb[ub * 200 + 150 + uj];
            float ii = sig_(xi), ff = sig_(xf), gg = th_(xg), oo = sig_(xo);
            c = ff * c + ii * gg;
            float h = oo * th_(c);
            s.hs[ub][uj] = h;
            hlast = h;
            ((float4*)s.pres[cur ^ 1])[tid] = pf0;
        }
        __syncthreads();
        cur ^= 1;
    }
    if (upd) {
        cst[(size_t)(b0 + ub) * 50 + uj] = c;
        hst[(size_t)(b0 + ub) * 50 + uj] = hlast;
        out[(size_t)(b0 + ub) * 50 + uj] = hlast;
    }
}

// ---------------------------------------------------------------------------
// rec_fused: blocks 0..511 run rec1(ch) (2 batches/block); blocks 512..767
// run rec2(ch-1) as two independent 256-thread halves (4 batches/block).
// LDS = union = rec1's 23.5 KB -> rec1 occupancy unchanged; ~3 WGs/CU.
// Both paths are latency-bound -> co-residency fills each other's stalls.
// ---------------------------------------------------------------------------
__global__ __launch_bounds__(512, 4) void rec_fused(
    const float* __restrict__ pre1, const float* __restrict__ Whh1,
    float* __restrict__ h1seq, float* __restrict__ c1, int first1,
    const float* __restrict__ pre2, const float* __restrict__ Whh2,
    float* __restrict__ c2, float* __restrict__ h2st, float* __restrict__ out,
    int first2, int Tc)
{
    __shared__ FS sm;
    const int bx = blockIdx.x;
    const int tid = threadIdx.x;
    if (bx < 512) {
        rec1_body(sm.r1, tid, bx * 2, pre1, Whh1, h1seq, c1, Tc, first1);
    } else {
        const int h = tid >> 8;           // two independent halves
        rec2_body(sm.r2[h], tid & 255, (bx - 512) * 4 + h * 2,
                  pre2, Whh2, c2, h2st, out, Tc, first2);
    }
}

// Standalone rec2 (tail chunk) — R1 v4 exact form via the shared body.
__global__ __launch_bounds__(256, 4) void rec2k(
    const float* __restrict__ pre2, const float* __restrict__ Whh,
    float* __restrict__ cst, float* __restrict__ hst, float* __restrict__ out,
    int Tc, int first)
{
    __shared__ R2S s;
    rec2_body(s, threadIdx.x, blockIdx.x * 2, pre2, Whh, cst, hst, out, Tc, first);
}

// ---------------------------------------------------------------------------
extern "C" void kernel_launch(void* const* d_in, const int* in_sizes, int n_in,
                              void* d_out, int out_size, void* d_ws, size_t ws_size,
                              hipStream_t stream)
{
    const float* x    = (const float*)d_in[0];
    const float* Wih1 = (const float*)d_in[1];
    const float* Whh1 = (const float*)d_in[2];
    const float* bih1 = (const float*)d_in[3];
    const float* bhh1 = (const float*)d_in[4];
    const float* Wih2 = (const float*)d_in[5];
    const float* Whh2 = (const float*)d_in[6];
    const float* bih2 = (const float*)d_in[7];
    const float* bhh2 = (const float*)d_in[8];
    float* out = (float*)d_out;
    float* ws  = (float*)d_ws;

    int Tc = 64;   // R8: Tc=128 regresses rec1 ~30% via L3 pressure on pre1
    auto need = [](int tc) -> size_t {
        return ((size_t)tc * 1024 * (400 + 100 + 200) +
                (size_t)1024 * 100 + (size_t)1024 * 50 * 2) * sizeof(float);
    };
    while (Tc > 1 && need(Tc) > ws_size) Tc >>= 1;

    float* pre1 = ws;
    float* h1s  = pre1 + (size_t)Tc * 1024 * 400;
    float* pre2 = h1s  + (size_t)Tc * 1024 * 100;
    float* c1   = pre2 + (size_t)Tc * 1024 * 200;
    float* c2   = c1 + 1024 * 100;
    float* h2st = c2 + 1024 * 50;

    const int nch = TT / Tc;

    // Schedule (R9): software-pipeline layer-2 one chunk behind layer-1 so
    // rec2(ch-1) rides along inside rec1(ch)'s dispatch.
    //   g1(0); F(r1(0));
    //   for ch=1..nch-1: g2(ch-1); g1(ch); F(r1(ch) || r2(ch-1));
    //   g2(nch-1); r2(nch-1)
    gemm_pre<80, 40, 40, 400, true ><<<dim3(4, Tc * 8), 256, 0, stream>>>(
        x, Wih1, bih1, bhh1, pre1, 0);
    rec_fused<<<dim3(512), dim3(512), 0, stream>>>(
        pre1, Whh1, h1s, c1, 1, pre2, Whh2, c2, h2st, out, 0, Tc);

    for (int ch = 1; ch < nch; ch++) {
        int t0 = ch * Tc;
        gemm_pre<100, 52, 52, 200, false><<<dim3(2, Tc * 8), 256, 0, stream>>>(
            h1s, Wih2, bih2, bhh2, pre2, 0);                       // g2(ch-1)
        gemm_pre<80, 40, 40, 400, true ><<<dim3(4, Tc * 8), 256, 0, stream>>>(
            x, Wih1, bih1, bhh1, pre1, t0);                        // g1(ch)
        rec_fused<<<dim3(768), dim3(512), 0, stream>>>(            // r1(ch) || r2(ch-1)
            pre1, Whh1, h1s, c1, 0,
            pre2, Whh2, c2, h2st, out, (ch == 1) ? 1 : 0, Tc);
    }

    gemm_pre<100, 52, 52, 200, false><<<dim3(2, Tc * 8), 256, 0, stream>>>(
        h1s, Wih2, bih2, bhh2, pre2, 0);                           // g2(last)
    rec2k<<<dim3(512), dim3(256), 0, stream>>>(
        pre2, Whh2, c2, h2st, out, Tc, 0);                         // r2(last)
}

// Round 11
// 2429.811 us; speedup vs baseline: 1.1309x; 1.0117x over previous
//
#include <hip/hip_runtime.h>

#define BT 1024   // batch
#define TT 512    // total timesteps

__device__ __forceinline__ float sig_(float x) { return 1.f / (1.f + __expf(-x)); }
__device__ __forceinline__ float th_(float x)  { return 1.f - 2.f / (1.f + __expf(2.f * x)); }

// ---------------------------------------------------------------------------
// gemm_pre v3 building blocks (R5, proven) — shared by standalone kernels
// and the fused g1 path.
// ---------------------------------------------------------------------------
template <int KS, int KPAD, int KH, int N, bool XMODE>
__device__ __forceinline__ void gp_stage(
    const float* __restrict__ A, const float* __restrict__ W,
    float (&As)[128][KPAD], float (&Bs)[KPAD][128],
    int tid, int n0, int by, int t0, int k0)
{
    constexpr int NQH = KH / 4;
#pragma unroll
    for (int ii = tid; ii < 128 * NQH; ii += 256) {
        int r = ii / NQH, q = ii % NQH;
        const float* src;
        if (XMODE) {
            int b  = (by & 7) * 128 + r;
            int tl = by >> 3;
            src = A + ((size_t)b * TT + (t0 + tl)) * KS;
        } else {
            src = A + (size_t)(by * 128 + r) * KS;
        }
        *(float4*)&As[r][q * 4] = *(const float4*)(src + k0 + q * 4);
    }
#pragma unroll
    for (int ii = tid; ii < 128 * NQH; ii += 256) {
        int n = ii & 127, kq = ii >> 7;
        float4 v = make_float4(0.f, 0.f, 0.f, 0.f);
        if (n0 + n < N) v = *(const float4*)(W + (size_t)(n0 + n) * KS + k0 + kq * 4);
        Bs[kq * 4 + 0][n] = v.x; Bs[kq * 4 + 1][n] = v.y;
        Bs[kq * 4 + 2][n] = v.z; Bs[kq * 4 + 3][n] = v.w;
    }
}

template <int KPAD, int KH>
__device__ __forceinline__ void gp_compute(
    const float (&As)[128][KPAD], const float (&Bs)[KPAD][128],
    float (&acc)[8][8], int tx, int ty)
{
    for (int kk = 0; kk < KH; kk += 4) {
        float4 bv[4][2];
#pragma unroll
        for (int r = 0; r < 4; r++) {
            bv[r][0] = *(const float4*)&Bs[kk + r][tx * 8];
            bv[r][1] = *(const float4*)&Bs[kk + r][tx * 8 + 4];
        }
#pragma unroll
        for (int i = 0; i < 8; i++) {
            float4 av = *(const float4*)&As[ty + 16 * i][kk];
#pragma unroll
            for (int s = 0; s < 2; s++) {
                acc[i][s*4+0] = fmaf(av.x, bv[0][s].x, acc[i][s*4+0]);
                acc[i][s*4+0] = fmaf(av.y, bv[1][s].x, acc[i][s*4+0]);
                acc[i][s*4+0] = fmaf(av.z, bv[2][s].x, acc[i][s*4+0]);
                acc[i][s*4+0] = fmaf(av.w, bv[3][s].x, acc[i][s*4+0]);
                acc[i][s*4+1] = fmaf(av.x, bv[0][s].y, acc[i][s*4+1]);
                acc[i][s*4+1] = fmaf(av.y, bv[1][s].y, acc[i][s*4+1]);
                acc[i][s*4+1] = fmaf(av.z, bv[2][s].y, acc[i][s*4+1]);
                acc[i][s*4+1] = fmaf(av.w, bv[3][s].y, acc[i][s*4+1]);
                acc[i][s*4+2] = fmaf(av.x, bv[0][s].z, acc[i][s*4+2]);
                acc[i][s*4+2] = fmaf(av.y, bv[1][s].z, acc[i][s*4+2]);
                acc[i][s*4+2] = fmaf(av.z, bv[2][s].z, acc[i][s*4+2]);
                acc[i][s*4+2] = fmaf(av.w, bv[3][s].z, acc[i][s*4+2]);
                acc[i][s*4+3] = fmaf(av.x, bv[0][s].w, acc[i][s*4+3]);
                acc[i][s*4+3] = fmaf(av.y, bv[1][s].w, acc[i][s*4+3]);
                acc[i][s*4+3] = fmaf(av.z, bv[2][s].w, acc[i][s*4+3]);
                acc[i][s*4+3] = fmaf(av.w, bv[3][s].w, acc[i][s*4+3]);
            }
        }
    }
}

template <int KS, int KPAD, int KH0, int N, bool XMODE>
__device__ __forceinline__ void gemm_body(
    float (&As)[128][KPAD], float (&Bs)[KPAD][128],
    const float* __restrict__ A, const float* __restrict__ W,
    const float* __restrict__ bih, const float* __restrict__ bhh,
    float* __restrict__ out, int t0, int tid, int bx, int by)
{
    constexpr int KH1 = KS - KH0;
    const int n0 = bx * 128;
    const int Rbase = by * 128;
    const int tx = tid & 15, ty = tid >> 4;

    float acc[8][8];
#pragma unroll
    for (int i = 0; i < 8; i++)
#pragma unroll
        for (int j = 0; j < 8; j++) acc[i][j] = 0.f;

    gp_stage<KS, KPAD, KH0, N, XMODE>(A, W, As, Bs, tid, n0, by, t0, 0);
    __syncthreads();
    gp_compute<KPAD, KH0>(As, Bs, acc, tx, ty);
    __syncthreads();
    gp_stage<KS, KPAD, KH1, N, XMODE>(A, W, As, Bs, tid, n0, by, t0, KH0);
    __syncthreads();
    gp_compute<KPAD, KH1>(As, Bs, acc, tx, ty);

#pragma unroll
    for (int s = 0; s < 2; s++) {
        int n = n0 + tx * 8 + s * 4;
        if (n < N) {
            float4 bias;
            bias.x = bih[n] + bhh[n];         bias.y = bih[n + 1] + bhh[n + 1];
            bias.z = bih[n + 2] + bhh[n + 2]; bias.w = bih[n + 3] + bhh[n + 3];
#pragma unroll
            for (int i = 0; i < 8; i++) {
                size_t R = (size_t)Rbase + ty + 16 * i;
                float4 o;
                o.x = acc[i][s*4+0] + bias.x; o.y = acc[i][s*4+1] + bias.y;
                o.z = acc[i][s*4+2] + bias.z; o.w = acc[i][s*4+3] + bias.w;
                *(float4*)(out + R * N + n) = o;
            }
        }
    }
}

template <int KS, int KPAD, int KH0, int N, bool XMODE>
__global__ __launch_bounds__(256, 3) void gemm_pre(
    const float* __restrict__ A, const float* __restrict__ W,
    const float* __restrict__ bih, const float* __restrict__ bhh,
    float* __restrict__ out, int t0)
{
    __shared__ __align__(16) float As[128][KPAD];
    __shared__ __align__(16) float Bs[KPAD][128];
    gemm_body<KS, KPAD, KH0, N, XMODE>(As, Bs, A, W, bih, bhh, out, t0,
                                       threadIdx.x, blockIdx.x, blockIdx.y);
}

// ---------------------------------------------------------------------------
// rec bodies — byte-identical math to the R1 v4 kernels (proven plateau).
// LEDGER (do not retry on rec1): (512,2) remat+occupancy loss (R3); PIN ->
// AGPR shuffle neutral (R4); t-unroll x2 -> spill (R5); 1024-thr/1-WG (R6);
// volatile (R7). R9 proved SCHEDULING is the live lever (fusion r1||r2:
// 172 vs 193 serial). R10: also pull g1(ch+1) into the shadow — rec2
// blocks retire ~75-100 µs in, g1 blocks (issued last) flow into the
// freed slots while rec1 finishes. pre1 double-buffered (288 MB < ws).
// ---------------------------------------------------------------------------
struct __align__(16) R1S {
    float hs[2][100];
    float pres[2][800];
    float gbuf[5 * 4 * 2 * 100];
};
struct __align__(16) R2S {
    float hs[2][50];
    float pres[2][400];
    float gbuf[5 * 4 * 2 * 50];
};
struct __align__(16) G1S { float As[128][40]; float Bs[40][128]; };
union __align__(16) FS { R1S r1; R2S r2[2]; G1S g1; };   // 40 KB

__device__ __forceinline__ void rec1_body(
    R1S& s, int tid, int b0,
    const float* __restrict__ pre, const float* __restrict__ Whh,
    float* __restrict__ hseq, float* __restrict__ cst, int Tc, int first)
{
    const bool comp = tid < 500;
    const int j  = tid % 100;
    const int kq = tid / 100;

    float4 w[4][5];
    if (comp) {
#pragma unroll
        for (int g = 0; g < 4; g++) {
            const float4* W4 = (const float4*)(Whh + (size_t)(g * 100 + j) * 100);
#pragma unroll
            for (int q = 0; q < 5; q++) w[g][q] = W4[kq * 5 + q];
        }
    }

    const bool upd = tid < 200;
    const int ub = tid / 100, uj = tid % 100;
    float c = 0.f;
    if (upd) {
        float h = 0.f;
        if (!first) {
            h = hseq[((size_t)(Tc - 1) * BT + b0 + ub) * 100 + uj];
            c = cst[(size_t)(b0 + ub) * 100 + uj];
        }
        s.hs[ub][uj] = h;
        ((float4*)s.pres[0])[tid] = ((const float4*)(pre + (size_t)b0 * 400))[tid];
    }
    __syncthreads();

    int cur = 0;
    for (int t = 0; t < Tc; t++) {
        int tn = (t + 1 < Tc) ? (t + 1) : t;
        float4 pf0;
        if (upd)
            pf0 = ((const float4*)(pre + (size_t)tn * BT * 400 + (size_t)b0 * 400))[tid];

        if (comp) {
            float acc[4][2];
#pragma unroll
            for (int g = 0; g < 4; g++) { acc[g][0] = 0.f; acc[g][1] = 0.f; }
            const float4* h0 = (const float4*)s.hs[0];
            const float4* h1 = (const float4*)s.hs[1];
#pragma unroll
            for (int q = 0; q < 5; q++) {
                int f = kq * 5 + q;
                float4 v0 = h0[f], v1 = h1[f];
#pragma unroll
                for (int g = 0; g < 4; g++) {
                    float4 wq = w[g][q];
                    acc[g][0] = fmaf(wq.x, v0.x, acc[g][0]);
                    acc[g][0] = fmaf(wq.y, v0.y, acc[g][0]);
                    acc[g][0] = fmaf(wq.z, v0.z, acc[g][0]);
                    acc[g][0] = fmaf(wq.w, v0.w, acc[g][0]);
                    acc[g][1] = fmaf(wq.x, v1.x, acc[g][1]);
                    acc[g][1] = fmaf(wq.y, v1.y, acc[g][1]);
                    acc[g][1] = fmaf(wq.z, v1.z, acc[g][1]);
                    acc[g][1] = fmaf(wq.w, v1.w, acc[g][1]);
                }
            }
#pragma unroll
            for (int g = 0; g < 4; g++) {
                s.gbuf[((kq * 4 + g) * 2 + 0) * 100 + j] = acc[g][0];
                s.gbuf[((kq * 4 + g) * 2 + 1) * 100 + j] = acc[g][1];
            }
        }
        __syncthreads();

        if (upd) {
            const float* pb = s.pres[cur];
            float s0 = 0.f, s1 = 0.f, s2 = 0.f, s3 = 0.f;
#pragma unroll
            for (int q = 0; q < 5; q++) {
                int base = q * 800;
                s0 += s.gbuf[base + (0 * 2 + ub) * 100 + uj];
                s1 += s.gbuf[base + (1 * 2 + ub) * 100 + uj];
                s2 += s.gbuf[base + (2 * 2 + ub) * 100 + uj];
                s3 += s.gbuf[base + (3 * 2 + ub) * 100 + uj];
            }
            float xi = s0 + pb[ub * 400 + uj];
            float xf = s1 + pb[ub * 400 + 100 + uj];
            float xg = s2 + pb[ub * 400 + 200 + uj];
            float xo = s3 + pb[ub * 400 + 300 + uj];
            float ii = sig_(xi), ff = sig_(xf), gg = th_(xg), oo = sig_(xo);
            c = ff * c + ii * gg;
            float h = oo * th_(c);
            s.hs[ub][uj] = h;
            hseq[((size_t)t * BT + b0 + ub) * 100 + uj] = h;
            ((float4*)s.pres[cur ^ 1])[tid] = pf0;
        }
        __syncthreads();
        cur ^= 1;
    }
    if (upd) cst[(size_t)(b0 + ub) * 100 + uj] = c;
}

__device__ __forceinline__ void rec2_body(
    R2S& s, int tid, int b0,
    const float* __restrict__ pre2, const float* __restrict__ Whh,
    float* __restrict__ cst, float* __restrict__ hst, float* __restrict__ out,
    int Tc, int first)
{
    const bool comp = tid < 250;
    const int j  = tid % 50;
    const int kq = tid / 50;

    float2 w[4][5];
    if (comp) {
#pragma unroll
        for (int g = 0; g < 4; g++) {
            const float2* W2 = (const float2*)(Whh + (size_t)(g * 50 + j) * 50);
#pragma unroll
            for (int q = 0; q < 5; q++) w[g][q] = W2[kq * 5 + q];
        }
    }

    const bool upd = tid < 100;
    const int ub = tid / 50, uj = tid % 50;
    float c = 0.f, hlast = 0.f;
    if (upd) {
        float h = 0.f;
        if (!first) {
            h = hst[(size_t)(b0 + ub) * 50 + uj];
            c = cst[(size_t)(b0 + ub) * 50 + uj];
        }
        s.hs[ub][uj] = h;
        hlast = h;
        ((float4*)s.pres[0])[tid] = ((const float4*)(pre2 + (size_t)b0 * 200))[tid];
    }
    __syncthreads();

    int cur = 0;
    for (int t = 0; t < Tc; t++) {
        int tn = (t + 1 < Tc) ? (t + 1) : t;
        float4 pf0;
        if (upd)
            pf0 = ((const float4*)(pre2 + (size_t)tn * BT * 200 + (size_t)b0 * 200))[tid];

        if (comp) {
            float acc[4][2];
#pragma unroll
            for (int g = 0; g < 4; g++) { acc[g][0] = 0.f; acc[g][1] = 0.f; }
            const float2* hA = (const float2*)s.hs[0];
            const float2* hB = (const float2*)s.hs[1];
#pragma unroll
            for (int q = 0; q < 5; q++) {
                int f = kq * 5 + q;
                float2 v0 = hA[f], v1 = hB[f];
#pragma unroll
                for (int g = 0; g < 4; g++) {
                    float2 wq = w[g][q];
                    acc[g][0] = fmaf(wq.x, v0.x, acc[g][0]);
                    acc[g][0] = fmaf(wq.y, v0.y, acc[g][0]);
                    acc[g][1] = fmaf(wq.x, v1.x, acc[g][1]);
                    acc[g][1] = fmaf(wq.y, v1.y, acc[g][1]);
                }
            }
#pragma unroll
            for (int g = 0; g < 4; g++) {
                s.gbuf[((kq * 4 + g) * 2 + 0) * 50 + j] = acc[g][0];
                s.gbuf[((kq * 4 + g) * 2 + 1) * 50 + j] = acc[g][1];
            }
        }
        __syncthreads();

        if (upd) {
            const float* pb = s.pres[cur];
            float s0 = 0.f, s1 = 0.f, s2 = 0.f, s3 = 0.f;
#pragma unroll
            for (int q = 0; q < 5; q++) {
                int base = q * 400;
                s0 += s.gbuf[base + (0 * 2 + ub) * 50 + uj];
                s1 += s.gbuf[base + (1 * 2 + ub) * 50 + uj];
                s2 += s.gbuf[base + (2 * 2 + ub) * 50 + uj];
                s3 += s.gbuf[base + (3 * 2 + ub) * 50 + uj];
            }
            float xi = s0 + pb[ub * 200 + uj];
            float xf = s1 + pb[ub * 200 + 50 + uj];
            float xg = s2 + pb[ub * 200 + 100 + uj];
            float xo = s3 + pb[ub * 200 + 150 + uj];
            float ii = sig_(xi), ff = sig_(xf), gg = th_(xg), oo = sig_(xo);
            c = ff * c + ii * gg;
            float h = oo * th_(c);
            s.hs[ub][uj] = h;
            hlast = h;
            ((float4*)s.pres[cur ^ 1])[tid] = pf0;
        }
        __syncthreads();
        cur ^= 1;
    }
    if (upd) {
        cst[(size_t)(b0 + ub) * 50 + uj] = c;
        hst[(size_t)(b0 + ub) * 50 + uj] = hlast;
        out[(size_t)(b0 + ub) * 50 + uj] = hlast;
    }
}

// ---------------------------------------------------------------------------
// rec_fused2: blocks [0,512) r1(ch); [512,768) r2(ch-1) x2 halves (if
// has_r2); remaining 2048 blocks run g1(ch+1) (256-thread gemm v3 body,
// waves 4..7 retire immediately; CDNA barriers release on active waves).
// Block ORDER puts g1 last so rec blocks fill CUs first and g1 streams
// into slots freed by retiring rec2 blocks. LDS = union = 40 KB.
// ---------------------------------------------------------------------------
__global__ __launch_bounds__(512, 4) void rec_fused2(
    const float* __restrict__ pre1r, const float* __restrict__ Whh1,
    float* __restrict__ h1seq, float* __restrict__ c1, int first1,
    const float* __restrict__ pre2, const float* __restrict__ Whh2,
    float* __restrict__ c2, float* __restrict__ h2st, float* __restrict__ out,
    int first2, int has_r2,
    const float* __restrict__ x, const float* __restrict__ Wih1,
    const float* __restrict__ bih1, const float* __restrict__ bhh1,
    float* __restrict__ pre1w, int t0n, int Tc)
{
    __shared__ FS sm;
    const int bx = blockIdx.x;
    const int tid = threadIdx.x;
    if (bx < 512) {
        rec1_body(sm.r1, tid, bx * 2, pre1r, Whh1, h1seq, c1, Tc, first1);
    } else if (has_r2 && bx < 768) {
        const int h = tid >> 8;
        rec2_body(sm.r2[h], tid & 255, (bx - 512) * 4 + h * 2,
                  pre2, Whh2, c2, h2st, out, Tc, first2);
    } else {
        if (tid >= 256) return;                      // waves 4..7 retire
        const int gid = bx - (has_r2 ? 768 : 512);
        gemm_body<80, 40, 40, 400, true>(sm.g1.As, sm.g1.Bs,
            x, Wih1, bih1, bhh1, pre1w, t0n, tid, gid & 3, gid >> 2);
    }
}

// Standalone rec2 (tail chunk).
__global__ __launch_bounds__(256, 4) void rec2k(
    const float* __restrict__ pre2, const float* __restrict__ Whh,
    float* __restrict__ cst, float* __restrict__ hst, float* __restrict__ out,
    int Tc, int first)
{
    __shared__ R2S s;
    rec2_body(s, threadIdx.x, blockIdx.x * 2, pre2, Whh, cst, hst, out, Tc, first);
}

// ---------------------------------------------------------------------------
extern "C" void kernel_launch(void* const* d_in, const int* in_sizes, int n_in,
                              void* d_out, int out_size, void* d_ws, size_t ws_size,
                              hipStream_t stream)
{
    const float* x    = (const float*)d_in[0];
    const float* Wih1 = (const float*)d_in[1];
    const float* Whh1 = (const float*)d_in[2];
    const float* bih1 = (const float*)d_in[3];
    const float* bhh1 = (const float*)d_in[4];
    const float* Wih2 = (const float*)d_in[5];
    const float* Whh2 = (const float*)d_in[6];
    const float* bih2 = (const float*)d_in[7];
    const float* bhh2 = (const float*)d_in[8];
    float* out = (float*)d_out;
    float* ws  = (float*)d_ws;

    int Tc = 64;   // R8: Tc=128 regresses rec1 ~30% (L3 pressure on pre1)
    auto need = [](int tc) -> size_t {
        return ((size_t)tc * 1024 * (400 * 2 + 100 + 200) +
                (size_t)1024 * 100 + (size_t)1024 * 50 * 2) * sizeof(float);
    };
    while (Tc > 1 && need(Tc) > ws_size) Tc >>= 1;

    float* pre1a = ws;
    float* pre1b = pre1a + (size_t)Tc * 1024 * 400;
    float* h1s   = pre1b + (size_t)Tc * 1024 * 400;
    float* pre2  = h1s   + (size_t)Tc * 1024 * 100;
    float* c1    = pre2  + (size_t)Tc * 1024 * 200;
    float* c2    = c1 + 1024 * 100;
    float* h2st  = c2 + 1024 * 50;
    float* p1[2] = { pre1a, pre1b };

    const int nch = TT / Tc;

    // R10 schedule: g1(0); then per chunk {g2(ch-1); F2: r1(ch)||r2(ch-1)||
    // g1(ch+1)}; tail g2+r2. pre1 double-buffered so g1(ch+1) can write
    // while r1(ch) reads.
    gemm_pre<80, 40, 40, 400, true ><<<dim3(4, Tc * 8), 256, 0, stream>>>(
        x, Wih1, bih1, bhh1, p1[0], 0);

    for (int ch = 0; ch < nch; ch++) {
        if (ch >= 1)
            gemm_pre<100, 52, 52, 200, false><<<dim3(2, Tc * 8), 256, 0, stream>>>(
                h1s, Wih2, bih2, bhh2, pre2, 0);               // g2(ch-1)
        int has_r2 = (ch >= 1) ? 1 : 0;
        int has_g1 = (ch + 1 < nch) ? 1 : 0;
        int nb = 512 + (has_r2 ? 256 : 0) + (has_g1 ? 2048 : 0);
        rec_fused2<<<dim3(nb), dim3(512), 0, stream>>>(
            p1[ch & 1], Whh1, h1s, c1, (ch == 0) ? 1 : 0,
            pre2, Whh2, c2, h2st, out, (ch == 1) ? 1 : 0, has_r2,
            x, Wih1, bih1, bhh1, p1[(ch + 1) & 1], (ch + 1) * Tc, Tc);
    }

    gemm_pre<100, 52, 52, 200, false><<<dim3(2, Tc * 8), 256, 0, stream>>>(
        h1s, Wih2, bih2, bhh2, pre2, 0);                       // g2(last)
    rec2k<<<dim3(512), dim3(256), 0, stream>>>(
        pre2, Whh2, c2, h2st, out, Tc, 0);                     // r2(last)
}

// Round 12
// 2383.006 us; speedup vs baseline: 1.1531x; 1.0196x over previous
//
#include <hip/hip_runtime.h>

#define BT 1024   // batch
#define TT 512    // total timesteps

__device__ __forceinline__ float sig_(float x) { return 1.f / (1.f + __expf(-x)); }
__device__ __forceinline__ float th_(float x)  { return 1.f - 2.f / (1.f + __expf(2.f * x)); }

// ---------------------------------------------------------------------------
// gemm_pre v4 = v3 with the Bs column mapping split (tx*4 | tx*4+64):
// R11 fix — v3's bv reads at tx*8 were 4-way bank-conflicted (32B lane
// stride); tx*4 stride-16B is 2-way = free (m136). Same math, same LDS.
// ---------------------------------------------------------------------------
template <int KS, int KPAD, int KH, int N, bool XMODE>
__device__ __forceinline__ void gp_stage(
    const float* __restrict__ A, const float* __restrict__ W,
    float (&As)[128][KPAD], float (&Bs)[KPAD][128],
    int tid, int n0, int by, int t0, int k0)
{
    constexpr int NQH = KH / 4;
#pragma unroll
    for (int ii = tid; ii < 128 * NQH; ii += 256) {
        int r = ii / NQH, q = ii % NQH;
        const float* src;
        if (XMODE) {
            int b  = (by & 7) * 128 + r;
            int tl = by >> 3;
            src = A + ((size_t)b * TT + (t0 + tl)) * KS;
        } else {
            src = A + (size_t)(by * 128 + r) * KS;
        }
        *(float4*)&As[r][q * 4] = *(const float4*)(src + k0 + q * 4);
    }
#pragma unroll
    for (int ii = tid; ii < 128 * NQH; ii += 256) {
        int n = ii & 127, kq = ii >> 7;
        float4 v = make_float4(0.f, 0.f, 0.f, 0.f);
        if (n0 + n < N) v = *(const float4*)(W + (size_t)(n0 + n) * KS + k0 + kq * 4);
        Bs[kq * 4 + 0][n] = v.x; Bs[kq * 4 + 1][n] = v.y;
        Bs[kq * 4 + 2][n] = v.z; Bs[kq * 4 + 3][n] = v.w;
    }
}

template <int KPAD, int KH>
__device__ __forceinline__ void gp_compute(
    const float (&As)[128][KPAD], const float (&Bs)[KPAD][128],
    float (&acc)[8][8], int tx, int ty)
{
    for (int kk = 0; kk < KH; kk += 4) {
        float4 bv[4][2];
#pragma unroll
        for (int r = 0; r < 4; r++) {
            bv[r][0] = *(const float4*)&Bs[kk + r][tx * 4];        // banks tx*4: 2-way, free
            bv[r][1] = *(const float4*)&Bs[kk + r][tx * 4 + 64];
        }
#pragma unroll
        for (int i = 0; i < 8; i++) {
            float4 av = *(const float4*)&As[ty + 16 * i][kk];
#pragma unroll
            for (int s = 0; s < 2; s++) {
                acc[i][s*4+0] = fmaf(av.x, bv[0][s].x, acc[i][s*4+0]);
                acc[i][s*4+0] = fmaf(av.y, bv[1][s].x, acc[i][s*4+0]);
                acc[i][s*4+0] = fmaf(av.z, bv[2][s].x, acc[i][s*4+0]);
                acc[i][s*4+0] = fmaf(av.w, bv[3][s].x, acc[i][s*4+0]);
                acc[i][s*4+1] = fmaf(av.x, bv[0][s].y, acc[i][s*4+1]);
                acc[i][s*4+1] = fmaf(av.y, bv[1][s].y, acc[i][s*4+1]);
                acc[i][s*4+1] = fmaf(av.z, bv[2][s].y, acc[i][s*4+1]);
                acc[i][s*4+1] = fmaf(av.w, bv[3][s].y, acc[i][s*4+1]);
                acc[i][s*4+2] = fmaf(av.x, bv[0][s].z, acc[i][s*4+2]);
                acc[i][s*4+2] = fmaf(av.y, bv[1][s].z, acc[i][s*4+2]);
                acc[i][s*4+2] = fmaf(av.z, bv[2][s].z, acc[i][s*4+2]);
                acc[i][s*4+2] = fmaf(av.w, bv[3][s].z, acc[i][s*4+2]);
                acc[i][s*4+3] = fmaf(av.x, bv[0][s].w, acc[i][s*4+3]);
                acc[i][s*4+3] = fmaf(av.y, bv[1][s].w, acc[i][s*4+3]);
                acc[i][s*4+3] = fmaf(av.z, bv[2][s].w, acc[i][s*4+3]);
                acc[i][s*4+3] = fmaf(av.w, bv[3][s].w, acc[i][s*4+3]);
            }
        }
    }
}

template <int KS, int KPAD, int KH0, int N, bool XMODE>
__device__ __forceinline__ void gemm_body(
    float (&As)[128][KPAD], float (&Bs)[KPAD][128],
    const float* __restrict__ A, const float* __restrict__ W,
    const float* __restrict__ bih, const float* __restrict__ bhh,
    float* __restrict__ out, int t0, int tid, int bx, int by)
{
    constexpr int KH1 = KS - KH0;
    const int n0 = bx * 128;
    const int Rbase = by * 128;
    const int tx = tid & 15, ty = tid >> 4;

    float acc[8][8];
#pragma unroll
    for (int i = 0; i < 8; i++)
#pragma unroll
        for (int j = 0; j < 8; j++) acc[i][j] = 0.f;

    gp_stage<KS, KPAD, KH0, N, XMODE>(A, W, As, Bs, tid, n0, by, t0, 0);
    __syncthreads();
    gp_compute<KPAD, KH0>(As, Bs, acc, tx, ty);
    __syncthreads();
    gp_stage<KS, KPAD, KH1, N, XMODE>(A, W, As, Bs, tid, n0, by, t0, KH0);
    __syncthreads();
    gp_compute<KPAD, KH1>(As, Bs, acc, tx, ty);

#pragma unroll
    for (int s = 0; s < 2; s++) {
        int n = n0 + tx * 4 + s * 64;                 // matches new bv mapping
        if (n < N) {
            float4 bias;
            bias.x = bih[n] + bhh[n];         bias.y = bih[n + 1] + bhh[n + 1];
            bias.z = bih[n + 2] + bhh[n + 2]; bias.w = bih[n + 3] + bhh[n + 3];
#pragma unroll
            for (int i = 0; i < 8; i++) {
                size_t R = (size_t)Rbase + ty + 16 * i;
                float4 o;
                o.x = acc[i][s*4+0] + bias.x; o.y = acc[i][s*4+1] + bias.y;
                o.z = acc[i][s*4+2] + bias.z; o.w = acc[i][s*4+3] + bias.w;
                *(float4*)(out + R * N + n) = o;
            }
        }
    }
}

template <int KS, int KPAD, int KH0, int N, bool XMODE>
__global__ __launch_bounds__(256, 3) void gemm_pre(
    const float* __restrict__ A, const float* __restrict__ W,
    const float* __restrict__ bih, const float* __restrict__ bhh,
    float* __restrict__ out, int t0)
{
    __shared__ __align__(16) float As[128][KPAD];
    __shared__ __align__(16) float Bs[KPAD][128];
    gemm_body<KS, KPAD, KH0, N, XMODE>(As, Bs, A, W, bih, bhh, out, t0,
                                       threadIdx.x, blockIdx.x, blockIdx.y);
}

// ---------------------------------------------------------------------------
// rec bodies — math unchanged (R1 v4 plateau). R11 adds s_setprio(1):
// rec waves are serial dependence chains; g1 blocks are elastic throughput
// work. Priority makes the CU scheduler issue rec's ready instrs first and
// fill only genuine stalls with g1 (T5 role-split regime).
// LEDGER (rec1, do not retry): (512,2) R3; PIN R4; unroll x2 R5; 1024-thr
// R6; volatile R7. Scheduling is the live lever (R9/R10).
// ---------------------------------------------------------------------------
struct __align__(16) R1S {
    float hs[2][100];
    float pres[2][800];
    float gbuf[5 * 4 * 2 * 100];
};
struct __align__(16) R2S {
    float hs[2][50];
    float pres[2][400];
    float gbuf[5 * 4 * 2 * 50];
};
struct __align__(16) G1S { float As[128][40]; float Bs[40][128]; };
union __align__(16) FS { R1S r1; R2S r2[2]; G1S g1; };   // 40 KB

__device__ __forceinline__ void rec1_body(
    R1S& s, int tid, int b0,
    const float* __restrict__ pre, const float* __restrict__ Whh,
    float* __restrict__ hseq, float* __restrict__ cst, int Tc, int first)
{
    __builtin_amdgcn_s_setprio(1);
    const bool comp = tid < 500;
    const int j  = tid % 100;
    const int kq = tid / 100;

    float4 w[4][5];
    if (comp) {
#pragma unroll
        for (int g = 0; g < 4; g++) {
            const float4* W4 = (const float4*)(Whh + (size_t)(g * 100 + j) * 100);
#pragma unroll
            for (int q = 0; q < 5; q++) w[g][q] = W4[kq * 5 + q];
        }
    }

    const bool upd = tid < 200;
    const int ub = tid / 100, uj = tid % 100;
    float c = 0.f;
    if (upd) {
        float h = 0.f;
        if (!first) {
            h = hseq[((size_t)(Tc - 1) * BT + b0 + ub) * 100 + uj];
            c = cst[(size_t)(b0 + ub) * 100 + uj];
        }
        s.hs[ub][uj] = h;
        ((float4*)s.pres[0])[tid] = ((const float4*)(pre + (size_t)b0 * 400))[tid];
    }
    __syncthreads();

    int cur = 0;
    for (int t = 0; t < Tc; t++) {
        int tn = (t + 1 < Tc) ? (t + 1) : t;
        float4 pf0;
        if (upd)
            pf0 = ((const float4*)(pre + (size_t)tn * BT * 400 + (size_t)b0 * 400))[tid];

        if (comp) {
            float acc[4][2];
#pragma unroll
            for (int g = 0; g < 4; g++) { acc[g][0] = 0.f; acc[g][1] = 0.f; }
            const float4* h0 = (const float4*)s.hs[0];
            const float4* h1 = (const float4*)s.hs[1];
#pragma unroll
            for (int q = 0; q < 5; q++) {
                int f = kq * 5 + q;
                float4 v0 = h0[f], v1 = h1[f];
#pragma unroll
                for (int g = 0; g < 4; g++) {
                    float4 wq = w[g][q];
                    acc[g][0] = fmaf(wq.x, v0.x, acc[g][0]);
                    acc[g][0] = fmaf(wq.y, v0.y, acc[g][0]);
                    acc[g][0] = fmaf(wq.z, v0.z, acc[g][0]);
                    acc[g][0] = fmaf(wq.w, v0.w, acc[g][0]);
                    acc[g][1] = fmaf(wq.x, v1.x, acc[g][1]);
                    acc[g][1] = fmaf(wq.y, v1.y, acc[g][1]);
                    acc[g][1] = fmaf(wq.z, v1.z, acc[g][1]);
                    acc[g][1] = fmaf(wq.w, v1.w, acc[g][1]);
                }
            }
#pragma unroll
            for (int g = 0; g < 4; g++) {
                s.gbuf[((kq * 4 + g) * 2 + 0) * 100 + j] = acc[g][0];
                s.gbuf[((kq * 4 + g) * 2 + 1) * 100 + j] = acc[g][1];
            }
        }
        __syncthreads();

        if (upd) {
            const float* pb = s.pres[cur];
            float s0 = 0.f, s1 = 0.f, s2 = 0.f, s3 = 0.f;
#pragma unroll
            for (int q = 0; q < 5; q++) {
                int base = q * 800;
                s0 += s.gbuf[base + (0 * 2 + ub) * 100 + uj];
                s1 += s.gbuf[base + (1 * 2 + ub) * 100 + uj];
                s2 += s.gbuf[base + (2 * 2 + ub) * 100 + uj];
                s3 += s.gbuf[base + (3 * 2 + ub) * 100 + uj];
            }
            float xi = s0 + pb[ub * 400 + uj];
            float xf = s1 + pb[ub * 400 + 100 + uj];
            float xg = s2 + pb[ub * 400 + 200 + uj];
            float xo = s3 + pb[ub * 400 + 300 + uj];
            float ii = sig_(xi), ff = sig_(xf), gg = th_(xg), oo = sig_(xo);
            c = ff * c + ii * gg;
            float h = oo * th_(c);
            s.hs[ub][uj] = h;
            hseq[((size_t)t * BT + b0 + ub) * 100 + uj] = h;
            ((float4*)s.pres[cur ^ 1])[tid] = pf0;
        }
        __syncthreads();
        cur ^= 1;
    }
    if (upd) cst[(size_t)(b0 + ub) * 100 + uj] = c;
    __builtin_amdgcn_s_setprio(0);
}

__device__ __forceinline__ void rec2_body(
    R2S& s, int tid, int b0,
    const float* __restrict__ pre2, const float* __restrict__ Whh,
    float* __restrict__ cst, float* __restrict__ hst, float* __restrict__ out,
    int Tc, int first)
{
    __builtin_amdgcn_s_setprio(1);
    const bool comp = tid < 250;
    const int j  = tid % 50;
    const int kq = tid / 50;

    float2 w[4][5];
    if (comp) {
#pragma unroll
        for (int g = 0; g < 4; g++) {
            const float2* W2 = (const float2*)(Whh + (size_t)(g * 50 + j) * 50);
#pragma unroll
            for (int q = 0; q < 5; q++) w[g][q] = W2[kq * 5 + q];
        }
    }

    const bool upd = tid < 100;
    const int ub = tid / 50, uj = tid % 50;
    float c = 0.f, hlast = 0.f;
    if (upd) {
        float h = 0.f;
        if (!first) {
            h = hst[(size_t)(b0 + ub) * 50 + uj];
            c = cst[(size_t)(b0 + ub) * 50 + uj];
        }
        s.hs[ub][uj] = h;
        hlast = h;
        ((float4*)s.pres[0])[tid] = ((const float4*)(pre2 + (size_t)b0 * 200))[tid];
    }
    __syncthreads();

    int cur = 0;
    for (int t = 0; t < Tc; t++) {
        int tn = (t + 1 < Tc) ? (t + 1) : t;
        float4 pf0;
        if (upd)
            pf0 = ((const float4*)(pre2 + (size_t)tn * BT * 200 + (size_t)b0 * 200))[tid];

        if (comp) {
            float acc[4][2];
#pragma unroll
            for (int g = 0; g < 4; g++) { acc[g][0] = 0.f; acc[g][1] = 0.f; }
            const float2* hA = (const float2*)s.hs[0];
            const float2* hB = (const float2*)s.hs[1];
#pragma unroll
            for (int q = 0; q < 5; q++) {
                int f = kq * 5 + q;
                float2 v0 = hA[f], v1 = hB[f];
#pragma unroll
                for (int g = 0; g < 4; g++) {
                    float2 wq = w[g][q];
                    acc[g][0] = fmaf(wq.x, v0.x, acc[g][0]);
                    acc[g][0] = fmaf(wq.y, v0.y, acc[g][0]);
                    acc[g][1] = fmaf(wq.x, v1.x, acc[g][1]);
                    acc[g][1] = fmaf(wq.y, v1.y, acc[g][1]);
                }
            }
#pragma unroll
            for (int g = 0; g < 4; g++) {
                s.gbuf[((kq * 4 + g) * 2 + 0) * 50 + j] = acc[g][0];
                s.gbuf[((kq * 4 + g) * 2 + 1) * 50 + j] = acc[g][1];
            }
        }
        __syncthreads();

        if (upd) {
            const float* pb = s.pres[cur];
            float s0 = 0.f, s1 = 0.f, s2 = 0.f, s3 = 0.f;
#pragma unroll
            for (int q = 0; q < 5; q++) {
                int base = q * 400;
                s0 += s.gbuf[base + (0 * 2 + ub) * 50 + uj];
                s1 += s.gbuf[base + (1 * 2 + ub) * 50 + uj];
                s2 += s.gbuf[base + (2 * 2 + ub) * 50 + uj];
                s3 += s.gbuf[base + (3 * 2 + ub) * 50 + uj];
            }
            float xi = s0 + pb[ub * 200 + uj];
            float xf = s1 + pb[ub * 200 + 50 + uj];
            float xg = s2 + pb[ub * 200 + 100 + uj];
            float xo = s3 + pb[ub * 200 + 150 + uj];
            float ii = sig_(xi), ff = sig_(xf), gg = th_(xg), oo = sig_(xo);
            c = ff * c + ii * gg;
            float h = oo * th_(c);
            s.hs[ub][uj] = h;
            hlast = h;
            ((float4*)s.pres[cur ^ 1])[tid] = pf0;
        }
        __syncthreads();
        cur ^= 1;
    }
    if (upd) {
        cst[(size_t)(b0 + ub) * 50 + uj] = c;
        hst[(size_t)(b0 + ub) * 50 + uj] = hlast;
        out[(size_t)(b0 + ub) * 50 + uj] = hlast;
    }
    __builtin_amdgcn_s_setprio(0);
}

// ---------------------------------------------------------------------------
// rec_fused2 (R10 packing): [0,512) r1(ch); [512,768) r2(ch-1); rest g1(ch+1)
// at prio 0 (gemm body unchanged, waves 4..7 retire immediately).
// ---------------------------------------------------------------------------
__global__ __launch_bounds__(512, 4) void rec_fused2(
    const float* __restrict__ pre1r, const float* __restrict__ Whh1,
    float* __restrict__ h1seq, float* __restrict__ c1, int first1,
    const float* __restrict__ pre2, const float* __restrict__ Whh2,
    float* __restrict__ c2, float* __restrict__ h2st, float* __restrict__ out,
    int first2, int has_r2,
    const float* __restrict__ x, const float* __restrict__ Wih1,
    const float* __restrict__ bih1, const float* __restrict__ bhh1,
    float* __restrict__ pre1w, int t0n, int Tc)
{
    __shared__ FS sm;
    const int bx = blockIdx.x;
    const int tid = threadIdx.x;
    if (bx < 512) {
        rec1_body(sm.r1, tid, bx * 2, pre1r, Whh1, h1seq, c1, Tc, first1);
    } else if (has_r2 && bx < 768) {
        const int h = tid >> 8;
        rec2_body(sm.r2[h], tid & 255, (bx - 512) * 4 + h * 2,
                  pre2, Whh2, c2, h2st, out, Tc, first2);
    } else {
        if (tid >= 256) return;                      // waves 4..7 retire
        const int gid = bx - (has_r2 ? 768 : 512);
        gemm_body<80, 40, 40, 400, true>(sm.g1.As, sm.g1.Bs,
            x, Wih1, bih1, bhh1, pre1w, t0n, tid, gid & 3, gid >> 2);
    }
}

// Standalone rec2 (tail chunk).
__global__ __launch_bounds__(256, 4) void rec2k(
    const float* __restrict__ pre2, const float* __restrict__ Whh,
    float* __restrict__ cst, float* __restrict__ hst, float* __restrict__ out,
    int Tc, int first)
{
    __shared__ R2S s;
    rec2_body(s, threadIdx.x, blockIdx.x * 2, pre2, Whh, cst, hst, out, Tc, first);
}

// ---------------------------------------------------------------------------
extern "C" void kernel_launch(void* const* d_in, const int* in_sizes, int n_in,
                              void* d_out, int out_size, void* d_ws, size_t ws_size,
                              hipStream_t stream)
{
    const float* x    = (const float*)d_in[0];
    const float* Wih1 = (const float*)d_in[1];
    const float* Whh1 = (const float*)d_in[2];
    const float* bih1 = (const float*)d_in[3];
    const float* bhh1 = (const float*)d_in[4];
    const float* Wih2 = (const float*)d_in[5];
    const float* Whh2 = (const float*)d_in[6];
    const float* bih2 = (const float*)d_in[7];
    const float* bhh2 = (const float*)d_in[8];
    float* out = (float*)d_out;
    float* ws  = (float*)d_ws;

    int Tc = 64;   // R8: Tc=128 regresses rec1 ~30% (L3 pressure on pre1)
    auto need = [](int tc) -> size_t {
        return ((size_t)tc * 1024 * (400 * 2 + 100 + 200) +
                (size_t)1024 * 100 + (size_t)1024 * 50 * 2) * sizeof(float);
    };
    while (Tc > 1 && need(Tc) > ws_size) Tc >>= 1;

    float* pre1a = ws;
    float* pre1b = pre1a + (size_t)Tc * 1024 * 400;
    float* h1s   = pre1b + (size_t)Tc * 1024 * 400;
    float* pre2  = h1s   + (size_t)Tc * 1024 * 100;
    float* c1    = pre2  + (size_t)Tc * 1024 * 200;
    float* c2    = c1 + 1024 * 100;
    float* h2st  = c2 + 1024 * 50;
    float* p1[2] = { pre1a, pre1b };

    const int nch = TT / Tc;

    // R10 schedule: g1(0); per chunk {g2(ch-1); F2: r1(ch)||r2(ch-1)||g1(ch+1)};
    // tail g2 + r2. pre1 double-buffered.
    gemm_pre<80, 40, 40, 400, true ><<<dim3(4, Tc * 8), 256, 0, stream>>>(
        x, Wih1, bih1, bhh1, p1[0], 0);

    for (int ch = 0; ch < nch; ch++) {
        if (ch >= 1)
            gemm_pre<100, 52, 52, 200, false><<<dim3(2, Tc * 8), 256, 0, stream>>>(
                h1s, Wih2, bih2, bhh2, pre2, 0);               // g2(ch-1)
        int has_r2 = (ch >= 1) ? 1 : 0;
        int has_g1 = (ch + 1 < nch) ? 1 : 0;
        int nb = 512 + (has_r2 ? 256 : 0) + (has_g1 ? 2048 : 0);
        rec_fused2<<<dim3(nb), dim3(512), 0, stream>>>(
            p1[ch & 1], Whh1, h1s, c1, (ch == 0) ? 1 : 0,
            pre2, Whh2, c2, h2st, out, (ch == 1) ? 1 : 0, has_r2,
            x, Wih1, bih1, bhh1, p1[(ch + 1) & 1], (ch + 1) * Tc, Tc);
    }

    gemm_pre<100, 52, 52, 200, false><<<dim3(2, Tc * 8), 256, 0, stream>>>(
        h1s, Wih2, bih2, bhh2, pre2, 0);                       // g2(last)
    rec2k<<<dim3(512), dim3(256), 0, stream>>>(
        pre2, Whh2, c2, h2st, out, Tc, 0);                     // r2(last)
}